// Round 1
// baseline (6342.776 us; speedup 1.0000x reference)
//
#include <hip/hip_runtime.h>
#include <math.h>

#define HWSZ 16384
#define WID 128
#define HEI 128
#define CCH 192
#define BB 4

// db3 filters
__device__ __constant__ float c_lo[6] = {0.035226291882100656f, -0.08544127388224149f, -0.13501102001039084f,
                                         0.4598775021193313f, 0.8068915093133388f, 0.3326705529509569f};
__device__ __constant__ float c_hi[6] = {-0.3326705529509569f, 0.8068915093133388f, -0.4598775021193313f,
                                         -0.13501102001039084f, 0.08544127388224149f, 0.035226291882100656f};

// ---------------- LayerNorm over channel dim ----------------
__global__ __launch_bounds__(256) void k_ln(const float* __restrict__ x,
    const float* __restrict__ g, const float* __restrict__ bta, float* __restrict__ out)
{
    int pg = blockIdx.x * 256 + threadIdx.x;      // 0..65535
    int b = pg >> 14, p = pg & 16383;
    const float* xp = x + (size_t)b * CCH * HWSZ + p;
    float s = 0.f, s2 = 0.f;
    for (int c = 0; c < CCH; ++c) {
        float v = xp[(size_t)c * HWSZ];
        s += v; s2 += v * v;
    }
    float mu = s * (1.f / CCH);
    float var = s2 * (1.f / CCH) - mu * mu;
    float rs = rsqrtf(var + 1e-5f);
    float* op = out + (size_t)b * CCH * HWSZ + p;
    for (int c = 0; c < CCH; ++c) {
        float v = xp[(size_t)c * HWSZ];
        op[(size_t)c * HWSZ] = (v - mu) * rs * g[c] + bta[c];
    }
}

// ---------------- generic conv1x1 (GEMM-ish) ----------------
// out[(b*outCtot+outCoff+co)*HW + px] = [addsrc...] + sum_ci w[co*wld+ci]*in[(b*inCtot+inCoff+ci)*HW+px]
__global__ __launch_bounds__(256) void k_conv1x1(const float* __restrict__ in,
    const float* __restrict__ w, float* __restrict__ out, const float* __restrict__ addsrc,
    int Ci, int Co, int wld, int inCtot, int inCoff, int outCtot, int outCoff)
{
    int tid = threadIdx.x;
    int px = blockIdx.x * 256 + tid;
    int cob = blockIdx.y * 32;
    int b = blockIdx.z;
    float acc[32];
#pragma unroll
    for (int j = 0; j < 32; ++j) acc[j] = 0.f;
    for (int kc = 0; kc < Ci; kc += 16) {
        int klen = Ci - kc; if (klen > 16) klen = 16;
        float iv[16];
        if (klen == 16) {
#pragma unroll
            for (int kk = 0; kk < 16; ++kk)
                iv[kk] = in[(size_t)(b * inCtot + inCoff + kc + kk) * HWSZ + px];
        } else {
#pragma unroll
            for (int kk = 0; kk < 16; ++kk)
                iv[kk] = (kk < klen) ? in[(size_t)(b * inCtot + inCoff + kc + kk) * HWSZ + px] : 0.f;
        }
#pragma unroll
        for (int j = 0; j < 32; ++j) {
            int co = cob + j;
            if (co < Co) {
                const float* wr = w + (size_t)co * wld + kc;
                if (klen == 16) {
#pragma unroll
                    for (int kk = 0; kk < 16; ++kk) acc[j] += wr[kk] * iv[kk];
                } else {
                    for (int kk = 0; kk < klen; ++kk) acc[j] += wr[kk] * iv[kk];
                }
            }
        }
    }
#pragma unroll
    for (int j = 0; j < 32; ++j) {
        int co = cob + j;
        if (co < Co) {
            size_t oi = (size_t)(b * outCtot + outCoff + co) * HWSZ + px;
            float r = acc[j];
            if (addsrc) r += addsrc[oi];
            out[oi] = r;
        }
    }
}

// ---------------- depthwise 3x3, pad 1 ----------------
__global__ __launch_bounds__(256) void k_dwconv(const float* __restrict__ in,
    const float* __restrict__ w, float* __restrict__ out,
    int Hh, int Ww, int inCtot, int inCoff, int outCtot, int outCoff)
{
    int sp = Hh * Ww;
    int p = blockIdx.x * 256 + threadIdx.x;
    int c = blockIdx.y, b = blockIdx.z;
    if (p >= sp) return;
    int y = p / Ww, xq = p - y * Ww;
    const float* ip = in + (size_t)(b * inCtot + inCoff + c) * sp;
    float acc = 0.f;
#pragma unroll
    for (int dy = 0; dy < 3; ++dy) {
        int yy = y + dy - 1;
        if (yy < 0 || yy >= Hh) continue;
#pragma unroll
        for (int dx = 0; dx < 3; ++dx) {
            int xx = xq + dx - 1;
            if (xx < 0 || xx >= Ww) continue;
            acc += ip[yy * Ww + xx] * w[c * 9 + dy * 3 + dx];
        }
    }
    out[(size_t)(b * outCtot + outCoff + c) * sp + p] = acc;
}

// ---------------- DWT: stride-2 correlation with reversed filters, pad 4, out 66x66 ----------------
__global__ __launch_bounds__(256) void k_dwt(const float* __restrict__ xn, float* __restrict__ band, int bandId)
{
    int p = blockIdx.x * 256 + threadIdx.x;
    if (p >= 66 * 66) return;
    int c = blockIdx.y, b = blockIdx.z;
    int oh = p / 66, ow = p - oh * 66;
    const float* fa = (bandId < 2) ? c_lo : c_hi;   // vertical (rows)
    const float* fb = (bandId & 1) ? c_hi : c_lo;   // horizontal (cols)
    const float* ip = xn + (size_t)(b * CCH + c) * HWSZ;
    float acc = 0.f;
#pragma unroll
    for (int ki = 0; ki < 6; ++ki) {
        int ih = oh * 2 + ki - 4;
        if (ih < 0 || ih >= HEI) continue;
        float av = fa[5 - ki];
        float ra = 0.f;
#pragma unroll
        for (int kj = 0; kj < 6; ++kj) {
            int iw = ow * 2 + kj - 4;
            if (iw < 0 || iw >= WID) continue;
            ra += ip[ih * WID + iw] * fb[5 - kj];
        }
        acc += av * ra;
    }
    band[(size_t)(b * CCH + c) * 4356 + p] = acc;
}

// ---------------- IDWT: zero-insert upsample + correlate with unreversed filters, pad 1 ----------------
__global__ __launch_bounds__(256) void k_idwt(const float* __restrict__ filt, float* __restrict__ q, int bandId)
{
    int p = blockIdx.x * 256 + threadIdx.x;
    if (p >= HWSZ) return;
    int c = blockIdx.y, b = blockIdx.z;
    int oh = p >> 7, ow = p & 127;
    const float* fa = (bandId < 2) ? c_lo : c_hi;
    const float* fb = (bandId & 1) ? c_hi : c_lo;
    const float* ip = filt + (size_t)(b * CCH + c) * 4356;
    float acc = 0.f;
#pragma unroll
    for (int ki = 0; ki < 6; ++ki) {
        int t1 = oh + ki - 1;
        if (t1 < 0 || (t1 & 1)) continue;
        int r = t1 >> 1;
        if (r >= 66) continue;
        float av = fa[ki];
        float ra = 0.f;
#pragma unroll
        for (int kj = 0; kj < 6; ++kj) {
            int t2 = ow + kj - 1;
            if (t2 < 0 || (t2 & 1)) continue;
            int c2 = t2 >> 1;
            if (c2 >= 66) continue;
            ra += ip[r * 66 + c2] * fb[kj];
        }
        acc += av * ra;
    }
    size_t idx = (size_t)(b * CCH + c) * HWSZ + p;
    if (bandId == 0) q[idx] = acc; else q[idx] += acc;
}

// ---------------- per-row reciprocal L2 norms for q and k ----------------
__global__ __launch_bounds__(256) void k_rownorm(const float* __restrict__ q,
    const float* __restrict__ kv, float* __restrict__ rq, float* __restrict__ rk)
{
    int row = blockIdx.x;       // b*192 + c
    int which = blockIdx.y;     // 0 = q, 1 = k
    int b = row / CCH, c = row - b * CCH;
    const float* src = which ? (kv + (size_t)(b * 384 + c) * HWSZ)
                             : (q + (size_t)row * HWSZ);
    int t = threadIdx.x;
    float s = 0.f;
    for (int i = t; i < HWSZ; i += 256) { float v = src[i]; s += v * v; }
    for (int off = 32; off > 0; off >>= 1) s += __shfl_down(s, off, 64);
    __shared__ float wsum[4];
    if ((t & 63) == 0) wsum[t >> 6] = s;
    __syncthreads();
    if (t == 0) {
        float tot = wsum[0] + wsum[1] + wsum[2] + wsum[3];
        float r = 1.f / fmaxf(sqrtf(tot), 1e-12f);
        (which ? rk : rq)[row] = r;
    }
}

// ---------------- partial QK^T over an n-slice of 512 ----------------
__global__ __launch_bounds__(256) void k_qk_partial(const float* __restrict__ q,
    const float* __restrict__ kv, float* __restrict__ pS)
{
    int slice = blockIdx.x;   // 0..31
    int bh = blockIdx.y;      // 0..15
    int b = bh >> 2, h = bh & 3;
    __shared__ float qch[48][65];
    __shared__ float kch[48][65];
    float acc[3][3] = {{0.f}};
    int tid = threadIdx.x, dt = tid >> 4, et = tid & 15;
    const float* qbase = q + (size_t)(b * CCH + h * 48) * HWSZ;
    const float* kbase = kv + (size_t)(b * 384 + h * 48) * HWSZ;
    int n0s = slice * 512;
    for (int n0 = n0s; n0 < n0s + 512; n0 += 64) {
        for (int l = tid; l < 3072; l += 256) {
            int r = l >> 6, cc = l & 63;
            qch[r][cc] = qbase[(size_t)r * HWSZ + n0 + cc];
            kch[r][cc] = kbase[(size_t)r * HWSZ + n0 + cc];
        }
        __syncthreads();
#pragma unroll
        for (int nn = 0; nn < 64; ++nn) {
            float q0 = qch[dt][nn], q1 = qch[dt + 16][nn], q2 = qch[dt + 32][nn];
            float k0 = kch[et][nn], k1 = kch[et + 16][nn], k2 = kch[et + 32][nn];
            acc[0][0] += q0 * k0; acc[0][1] += q0 * k1; acc[0][2] += q0 * k2;
            acc[1][0] += q1 * k0; acc[1][1] += q1 * k1; acc[1][2] += q1 * k2;
            acc[2][0] += q2 * k0; acc[2][1] += q2 * k1; acc[2][2] += q2 * k2;
        }
        __syncthreads();
    }
    float* ps = pS + (size_t)(slice * 16 + bh) * 2304;
#pragma unroll
    for (int i = 0; i < 3; ++i)
#pragma unroll
        for (int j = 0; j < 3; ++j)
            ps[(dt + 16 * i) * 48 + (et + 16 * j)] = acc[i][j];
}

// ---------------- reduce partials, scale, softmax ----------------
__global__ __launch_bounds__(256) void k_attn_soft(const float* __restrict__ pS,
    const float* __restrict__ rq, const float* __restrict__ rk,
    const float* __restrict__ temp, float* __restrict__ attnw)
{
    int bh = blockIdx.x; int b = bh >> 2, h = bh & 3;
    __shared__ float S[48][49];
    int tid = threadIdx.x, dt = tid >> 4, et = tid & 15;
    float tv = temp[h];
#pragma unroll
    for (int i = 0; i < 3; ++i) {
#pragma unroll
        for (int j = 0; j < 3; ++j) {
            int d = dt + 16 * i, e = et + 16 * j;
            float s = 0.f;
            for (int sl = 0; sl < 32; ++sl)
                s += pS[(size_t)(sl * 16 + bh) * 2304 + d * 48 + e];
            S[d][e] = s * tv * rq[b * CCH + h * 48 + d] * rk[b * CCH + h * 48 + e];
        }
    }
    __syncthreads();
    if (tid < 48) {
        float mx = -1e30f;
        for (int e = 0; e < 48; ++e) mx = fmaxf(mx, S[tid][e]);
        float sum = 0.f;
        for (int e = 0; e < 48; ++e) sum += expf(S[tid][e] - mx);
        float inv = 1.f / sum;
        for (int e = 0; e < 48; ++e)
            attnw[((size_t)bh * 48 + tid) * 48 + e] = expf(S[tid][e] - mx) * inv;
    }
}

// ---------------- out = attn @ v ----------------
__global__ __launch_bounds__(256) void k_attn_v(const float* __restrict__ attnw,
    const float* __restrict__ kv, float* __restrict__ outp)
{
    int px = blockIdx.x * 256 + threadIdx.x;
    int dg = blockIdx.y;       // 0..5 (8 d's each)
    int bh = blockIdx.z; int b = bh >> 2, h = bh & 3;
    __shared__ float aw[8][48];
    for (int l = threadIdx.x; l < 8 * 48; l += 256) {
        int i = l / 48, e = l - 48 * i;
        aw[i][e] = attnw[((size_t)bh * 48 + dg * 8 + i) * 48 + e];
    }
    __syncthreads();
    const float* vbase = kv + (size_t)(b * 384 + 192 + h * 48) * HWSZ + px;
    float acc[8] = {0.f};
#pragma unroll
    for (int e = 0; e < 48; ++e) {
        float vv = vbase[(size_t)e * HWSZ];
#pragma unroll
        for (int i = 0; i < 8; ++i) acc[i] += aw[i][e] * vv;
    }
    float* ob = outp + (size_t)(b * CCH + h * 48 + dg * 8) * HWSZ + px;
#pragma unroll
    for (int i = 0; i < 8; ++i) ob[(size_t)i * HWSZ] = acc[i];
}

// ---------------- exact GELU(y1) * y2, in place into y1 ----------------
__global__ __launch_bounds__(256) void k_gelugate(float* __restrict__ y1,
    const float* __restrict__ y2, int n)
{
    int i = blockIdx.x * 256 + threadIdx.x;
    if (i < n) {
        float a = y1[i], b2 = y2[i];
        float g = 0.5f * a * (1.f + erff(a * 0.70710678118654752f));
        y1[i] = g * b2;
    }
}

// ---------------- launcher ----------------
extern "C" void kernel_launch(void* const* d_in, const int* in_sizes, int n_in,
                              void* d_out, int out_size, void* d_ws, size_t ws_size,
                              hipStream_t stream)
{
    const float* x     = (const float*)d_in[0];
    const float* ln1g  = (const float*)d_in[1];
    const float* ln1b  = (const float*)d_in[2];
    const float* ln2g  = (const float*)d_in[3];
    const float* ln2b  = (const float*)d_in[4];
    const float* temp  = (const float*)d_in[5];
    const float* wqkv  = (const float*)d_in[6];
    const float* wqkvd = (const float*)d_in[7];
    const float* w5    = (const float*)d_in[8];
    const float* w7    = (const float*)d_in[9];
    const float* w9    = (const float*)d_in[10];
    const float* wattn = (const float*)d_in[11];
    const float* wffni = (const float*)d_in[12];
    const float* wffnd = (const float*)d_in[13];
    const float* wffno = (const float*)d_in[14];
    float* out = (float*)d_out;

    // arena layout (bytes)
    const size_t OFF_XN  = 0;                  // 50,331,648  xn / attn-out / xn2
    const size_t OFF_KV  = 50331648;           // 100,663,296 kv   / ffn y buffers
    const size_t OFF_Q   = 150994944;          // 50,331,648  q
    const size_t OFF_TMP = 201326592;          // 26,763,264  band raw+filt / qkv tmp
    const size_t OFF_SM  = 228089856;          // small: rq, rk, attnw, partial S
    const size_t NEED    = OFF_SM + 262144 + 4718592;
    if (ws_size < NEED) return;   // signature: zero output (absmax == max|ref|)

    char* ws = (char*)d_ws;
    float* xn    = (float*)(ws + OFF_XN);
    float* kv    = (float*)(ws + OFF_KV);
    float* q     = (float*)(ws + OFF_Q);
    float* braw  = (float*)(ws + OFF_TMP);
    float* bfilt = braw + 13381632 / 4;
    float* tmp   = (float*)(ws + OFF_TMP);
    float* rq    = (float*)(ws + OFF_SM);
    float* rk    = rq + 1024;
    float* attnw = (float*)(ws + OFF_SM + 8192);
    float* pS    = (float*)(ws + OFF_SM + 262144);

    dim3 blk(256);

    // 1. xn = LN1(x)
    k_ln<<<256, blk, 0, stream>>>(x, ln1g, ln1b, xn);

    // 2. q = ssl(xn): per band dwt -> dw3x3 -> idwt accumulate
    for (int bd = 0; bd < 4; ++bd) {
        k_dwt<<<dim3(18, CCH, BB), blk, 0, stream>>>(xn, braw, bd);
        const float* wb = (bd <= 1) ? w5 : (bd == 2 ? w7 : w9);
        k_dwconv<<<dim3(18, CCH, BB), blk, 0, stream>>>(braw, wb, bfilt, 66, 66, CCH, 0, CCH, 0);
        k_idwt<<<dim3(64, CCH, BB), blk, 0, stream>>>(bfilt, q, bd);
    }

    // 3. kv = dw3x3(conv1x1(xn, w_qkv)) in 4 chunks of 96 channels
    for (int cc = 0; cc < 4; ++cc) {
        int c0 = cc * 96;
        k_conv1x1<<<dim3(64, 3, BB), blk, 0, stream>>>(xn, wqkv + (size_t)c0 * CCH, tmp, nullptr,
                                                       CCH, 96, CCH, CCH, 0, 96, 0);
        k_dwconv<<<dim3(64, 96, BB), blk, 0, stream>>>(tmp, wqkvd + (size_t)c0 * 9, kv,
                                                       HEI, WID, 96, 0, 384, c0);
    }

    // 4. row norms
    k_rownorm<<<dim3(768, 2), blk, 0, stream>>>(q, kv, rq, rk);

    // 5. attention weights
    k_qk_partial<<<dim3(32, 16), blk, 0, stream>>>(q, kv, pS);
    k_attn_soft<<<16, blk, 0, stream>>>(pS, rq, rk, temp, attnw);

    // 6. out_spatial = attn @ v  (reuse xn buffer)
    float* atto = xn;
    k_attn_v<<<dim3(64, 6, 16), blk, 0, stream>>>(attnw, kv, atto);

    // 7. d_out = x + conv1x1(atto, w_attn_out)
    k_conv1x1<<<dim3(64, 6, BB), blk, 0, stream>>>(atto, wattn, out, x,
                                                   CCH, CCH, CCH, CCH, 0, CCH, 0);

    // 8. xn2 = LN2(d_out)  (reuse xn buffer; atto consumed)
    float* xn2 = xn;
    k_ln<<<256, blk, 0, stream>>>(out, ln2g, ln2b, xn2);

    // 9. GDFN in 6 hid-chunks of <=96
    float* y1r = kv;
    float* y2r = kv + 25165824 / 4;
    float* y1d = kv + 50331648 / 4;
    float* y2d = kv + 75497472 / 4;
    for (int ck = 0; ck < 6; ++ck) {
        int i0 = ck * 96;
        int ch = 510 - i0; if (ch > 96) ch = 96;
        int gy = (ch + 31) / 32;
        k_conv1x1<<<dim3(64, gy, BB), blk, 0, stream>>>(xn2, wffni + (size_t)i0 * CCH, y1r, nullptr,
                                                        CCH, ch, CCH, CCH, 0, ch, 0);
        k_conv1x1<<<dim3(64, gy, BB), blk, 0, stream>>>(xn2, wffni + (size_t)(510 + i0) * CCH, y2r, nullptr,
                                                        CCH, ch, CCH, CCH, 0, ch, 0);
        k_dwconv<<<dim3(64, ch, BB), blk, 0, stream>>>(y1r, wffnd + (size_t)i0 * 9, y1d,
                                                       HEI, WID, ch, 0, ch, 0);
        k_dwconv<<<dim3(64, ch, BB), blk, 0, stream>>>(y2r, wffnd + (size_t)(510 + i0) * 9, y2d,
                                                       HEI, WID, ch, 0, ch, 0);
        int n = BB * ch * HWSZ;
        k_gelugate<<<(n + 255) / 256, blk, 0, stream>>>(y1d, y2d, n);
        k_conv1x1<<<dim3(64, 6, BB), blk, 0, stream>>>(y1d, wffno + i0, out, out,
                                                       ch, CCH, 510, ch, 0, CCH, 0);
    }
}

// Round 2
// 1949.848 us; speedup vs baseline: 3.2530x; 3.2530x over previous
//
#include <hip/hip_runtime.h>
#include <math.h>

#define HWSZ 16384
#define WID 128
#define HEI 128
#define CCH 192
#define BB 4

typedef short v8s __attribute__((ext_vector_type(8)));
typedef float f32x4 __attribute__((ext_vector_type(4)));

__device__ __constant__ float c_lo[6] = {0.035226291882100656f, -0.08544127388224149f, -0.13501102001039084f,
                                         0.4598775021193313f, 0.8068915093133388f, 0.3326705529509569f};
__device__ __constant__ float c_hi[6] = {-0.3326705529509569f, 0.8068915093133388f, -0.4598775021193313f,
                                         -0.13501102001039084f, 0.08544127388224149f, 0.035226291882100656f};

__device__ __forceinline__ float b2f(unsigned short h) { return __uint_as_float(((unsigned int)h) << 16); }
__device__ __forceinline__ unsigned short f2b(float f) {
    unsigned int u = __float_as_uint(f);
    return (unsigned short)((u + 0x7fffu + ((u >> 16) & 1u)) >> 16);
}
__device__ __forceinline__ unsigned int pk2(float a, float b) {
    return (unsigned int)f2b(a) | ((unsigned int)f2b(b) << 16);
}

// ---------------- weight fp32 -> bf16 with row/col zero-pad ----------------
__global__ __launch_bounds__(256) void k_wconv(const float* __restrict__ src,
    unsigned short* __restrict__ dst, int rows, int cols, int dcols, int total)
{
    int i = blockIdx.x * 256 + threadIdx.x;
    if (i >= total) return;
    int r = i / dcols, c = i - r * dcols;
    float v = (c < cols && r < rows) ? src[r * cols + c] : 0.f;
    dst[i] = f2b(v);
}

// ---------------- LayerNorm over channel dim; writes transposed bf16 (+opt fp32 spatial) ----------------
template<int WRITE_F32>
__global__ __launch_bounds__(256) void k_ln(const float* __restrict__ x,
    const float* __restrict__ g, const float* __restrict__ bta,
    float* __restrict__ xsp, unsigned short* __restrict__ xT)
{
    int pg = blockIdx.x * 256 + threadIdx.x;
    int b = pg >> 14, p = pg & 16383;
    const float* xp = x + (size_t)b * CCH * HWSZ + p;
    float s = 0.f, s2 = 0.f;
    for (int c = 0; c < CCH; ++c) {
        float v = xp[(size_t)c * HWSZ];
        s += v; s2 += v * v;
    }
    float mu = s * (1.f / CCH);
    float var = s2 * (1.f / CCH) - mu * mu;
    float rs = rsqrtf(var + 1e-5f);
    unsigned short* tr = xT + ((size_t)b * HWSZ + p) * CCH;
    float* sp = xsp + (size_t)b * CCH * HWSZ + p;
    for (int c0 = 0; c0 < CCH; c0 += 8) {
        float vv[8];
#pragma unroll
        for (int i = 0; i < 8; ++i) {
            float v = xp[(size_t)(c0 + i) * HWSZ];
            v = (v - mu) * rs * g[c0 + i] + bta[c0 + i];
            vv[i] = v;
            if (WRITE_F32) sp[(size_t)(c0 + i) * HWSZ] = v;
        }
        uint4 u;
        u.x = pk2(vv[0], vv[1]); u.y = pk2(vv[2], vv[3]);
        u.z = pk2(vv[4], vv[5]); u.w = pk2(vv[6], vv[7]);
        *(uint4*)(tr + c0) = u;
    }
}

// ---------------- bf16 MFMA GEMM: out[b][co][px] = sum_k W[co][k] * XT[b][px][k] ----------------
// X: bf16 [b][HW][ldx]; W: bf16 [M][ldw]; M = gridDim.y*64 (all launches M%64==0)
template<int OUT_BF16, int ADD>
__global__ __launch_bounds__(256) void k_gemm(
    const unsigned short* __restrict__ X, const unsigned short* __restrict__ W,
    void* __restrict__ outp, const float* __restrict__ addsrc,
    int K, int ldx, int ldw, int Mtot)
{
    int lane = threadIdx.x & 63, wv = threadIdx.x >> 6;
    int b = blockIdx.z;
    int r = lane & 15, koct = lane >> 4;
    int pxb = blockIdx.x * 256 + wv * 64;
    int co0 = blockIdx.y * 64;
    const unsigned short* xb = X + ((size_t)b * HWSZ + pxb + r) * ldx + koct * 8;
    const unsigned short* wb = W + (size_t)(co0 + r) * ldw + koct * 8;
    f32x4 z = {0.f, 0.f, 0.f, 0.f};
    f32x4 acc[4][4];
#pragma unroll
    for (int i = 0; i < 4; ++i)
#pragma unroll
        for (int j = 0; j < 4; ++j) acc[i][j] = z;

    for (int k0 = 0; k0 < K; k0 += 32) {
        v8s a0 = *(const v8s*)(wb + k0);
        v8s a1 = *(const v8s*)(wb + 16 * ldw + k0);
        v8s a2 = *(const v8s*)(wb + 32 * ldw + k0);
        v8s a3 = *(const v8s*)(wb + 48 * ldw + k0);
        v8s b0 = *(const v8s*)(xb + k0);
        v8s b1 = *(const v8s*)(xb + 16 * ldx + k0);
        v8s b2 = *(const v8s*)(xb + 32 * ldx + k0);
        v8s b3 = *(const v8s*)(xb + 48 * ldx + k0);
        acc[0][0] = __builtin_amdgcn_mfma_f32_16x16x32_bf16(a0, b0, acc[0][0], 0, 0, 0);
        acc[0][1] = __builtin_amdgcn_mfma_f32_16x16x32_bf16(a0, b1, acc[0][1], 0, 0, 0);
        acc[0][2] = __builtin_amdgcn_mfma_f32_16x16x32_bf16(a0, b2, acc[0][2], 0, 0, 0);
        acc[0][3] = __builtin_amdgcn_mfma_f32_16x16x32_bf16(a0, b3, acc[0][3], 0, 0, 0);
        acc[1][0] = __builtin_amdgcn_mfma_f32_16x16x32_bf16(a1, b0, acc[1][0], 0, 0, 0);
        acc[1][1] = __builtin_amdgcn_mfma_f32_16x16x32_bf16(a1, b1, acc[1][1], 0, 0, 0);
        acc[1][2] = __builtin_amdgcn_mfma_f32_16x16x32_bf16(a1, b2, acc[1][2], 0, 0, 0);
        acc[1][3] = __builtin_amdgcn_mfma_f32_16x16x32_bf16(a1, b3, acc[1][3], 0, 0, 0);
        acc[2][0] = __builtin_amdgcn_mfma_f32_16x16x32_bf16(a2, b0, acc[2][0], 0, 0, 0);
        acc[2][1] = __builtin_amdgcn_mfma_f32_16x16x32_bf16(a2, b1, acc[2][1], 0, 0, 0);
        acc[2][2] = __builtin_amdgcn_mfma_f32_16x16x32_bf16(a2, b2, acc[2][2], 0, 0, 0);
        acc[2][3] = __builtin_amdgcn_mfma_f32_16x16x32_bf16(a2, b3, acc[2][3], 0, 0, 0);
        acc[3][0] = __builtin_amdgcn_mfma_f32_16x16x32_bf16(a3, b0, acc[3][0], 0, 0, 0);
        acc[3][1] = __builtin_amdgcn_mfma_f32_16x16x32_bf16(a3, b1, acc[3][1], 0, 0, 0);
        acc[3][2] = __builtin_amdgcn_mfma_f32_16x16x32_bf16(a3, b2, acc[3][2], 0, 0, 0);
        acc[3][3] = __builtin_amdgcn_mfma_f32_16x16x32_bf16(a3, b3, acc[3][3], 0, 0, 0);
    }

    int row4 = koct * 4;
#pragma unroll
    for (int c = 0; c < 4; ++c) {
        int corow = co0 + c * 16 + row4;
#pragma unroll
        for (int nf = 0; nf < 4; ++nf) {
            int pxo = pxb + nf * 16 + r;
#pragma unroll
            for (int j = 0; j < 4; ++j) {
                size_t oi = ((size_t)b * Mtot + corow + j) * HWSZ + pxo;
                float v = acc[c][nf][j];
                if (ADD) v += addsrc[oi];
                if (OUT_BF16) ((unsigned short*)outp)[oi] = f2b(v);
                else ((float*)outp)[oi] = v;
            }
        }
    }
}

// ---------------- depthwise 3x3 fp32, pad 1 ----------------
__global__ __launch_bounds__(256) void k_dwconv(const float* __restrict__ in,
    const float* __restrict__ w, float* __restrict__ out,
    int Hh, int Ww, int inCtot, int inCoff, int outCtot, int outCoff)
{
    int sp = Hh * Ww;
    int p = blockIdx.x * 256 + threadIdx.x;
    int c = blockIdx.y, b = blockIdx.z;
    if (p >= sp) return;
    int y = p / Ww, xq = p - y * Ww;
    const float* ip = in + (size_t)(b * inCtot + inCoff + c) * sp;
    float acc = 0.f;
#pragma unroll
    for (int dy = 0; dy < 3; ++dy) {
        int yy = y + dy - 1;
        if (yy < 0 || yy >= Hh) continue;
#pragma unroll
        for (int dx = 0; dx < 3; ++dx) {
            int xx = xq + dx - 1;
            if (xx < 0 || xx >= Ww) continue;
            acc += ip[yy * Ww + xx] * w[c * 9 + dy * 3 + dx];
        }
    }
    out[(size_t)(b * outCtot + outCoff + c) * sp + p] = acc;
}

// ---------------- depthwise 3x3 bf16 (FFN path), Ctot=256 ----------------
__global__ __launch_bounds__(256) void k_dwconv_b(const unsigned short* __restrict__ in,
    const float* __restrict__ w, unsigned short* __restrict__ out, int validc)
{
    int p = blockIdx.x * 256 + threadIdx.x;
    int c = blockIdx.y, b = blockIdx.z;
    size_t obase = ((size_t)(b * 256 + c)) * HWSZ + p;
    if (c >= validc) { out[obase] = 0; return; }
    int y = p >> 7, xq = p & 127;
    const unsigned short* ip = in + ((size_t)(b * 256 + c)) * HWSZ;
    float acc = 0.f;
#pragma unroll
    for (int dy = 0; dy < 3; ++dy) {
        int yy = y + dy - 1;
        if (yy < 0 || yy >= HEI) continue;
#pragma unroll
        for (int dx = 0; dx < 3; ++dx) {
            int xx = xq + dx - 1;
            if (xx < 0 || xx >= WID) continue;
            acc += b2f(ip[yy * WID + xx]) * w[c * 9 + dy * 3 + dx];
        }
    }
    out[obase] = f2b(acc);
}

// ---------------- DWT: stride-2 correlation, pad 4, out 66x66 ----------------
__global__ __launch_bounds__(256) void k_dwt(const float* __restrict__ xn, float* __restrict__ band, int bandId)
{
    int p = blockIdx.x * 256 + threadIdx.x;
    if (p >= 66 * 66) return;
    int c = blockIdx.y, b = blockIdx.z;
    int oh = p / 66, ow = p - oh * 66;
    const float* fa = (bandId < 2) ? c_lo : c_hi;
    const float* fb = (bandId & 1) ? c_hi : c_lo;
    const float* ip = xn + (size_t)(b * CCH + c) * HWSZ;
    float acc = 0.f;
#pragma unroll
    for (int ki = 0; ki < 6; ++ki) {
        int ih = oh * 2 + ki - 4;
        if (ih < 0 || ih >= HEI) continue;
        float av = fa[5 - ki];
        float ra = 0.f;
#pragma unroll
        for (int kj = 0; kj < 6; ++kj) {
            int iw = ow * 2 + kj - 4;
            if (iw < 0 || iw >= WID) continue;
            ra += ip[ih * WID + iw] * fb[5 - kj];
        }
        acc += av * ra;
    }
    band[(size_t)(b * CCH + c) * 4356 + p] = acc;
}

// ---------------- IDWT ----------------
__global__ __launch_bounds__(256) void k_idwt(const float* __restrict__ filt, float* __restrict__ q, int bandId)
{
    int p = blockIdx.x * 256 + threadIdx.x;
    if (p >= HWSZ) return;
    int c = blockIdx.y, b = blockIdx.z;
    int oh = p >> 7, ow = p & 127;
    const float* fa = (bandId < 2) ? c_lo : c_hi;
    const float* fb = (bandId & 1) ? c_hi : c_lo;
    const float* ip = filt + (size_t)(b * CCH + c) * 4356;
    float acc = 0.f;
#pragma unroll
    for (int ki = 0; ki < 6; ++ki) {
        int t1 = oh + ki - 1;
        if (t1 < 0 || (t1 & 1)) continue;
        int r = t1 >> 1;
        if (r >= 66) continue;
        float av = fa[ki];
        float ra = 0.f;
#pragma unroll
        for (int kj = 0; kj < 6; ++kj) {
            int t2 = ow + kj - 1;
            if (t2 < 0 || (t2 & 1)) continue;
            int c2 = t2 >> 1;
            if (c2 >= 66) continue;
            ra += ip[r * 66 + c2] * fb[kj];
        }
        acc += av * ra;
    }
    size_t idx = (size_t)(b * CCH + c) * HWSZ + p;
    if (bandId == 0) q[idx] = acc; else q[idx] += acc;
}

// ---------------- per-row reciprocal L2 norms ----------------
__global__ __launch_bounds__(256) void k_rownorm(const float* __restrict__ q,
    const float* __restrict__ kv, float* __restrict__ rq, float* __restrict__ rk)
{
    int row = blockIdx.x;
    int which = blockIdx.y;
    int b = row / CCH, c = row - b * CCH;
    const float* src = which ? (kv + (size_t)(b * 384 + c) * HWSZ)
                             : (q + (size_t)row * HWSZ);
    int t = threadIdx.x;
    float s = 0.f;
    for (int i = t; i < HWSZ; i += 256) { float v = src[i]; s += v * v; }
    for (int off = 32; off > 0; off >>= 1) s += __shfl_down(s, off, 64);
    __shared__ float wsum[4];
    if ((t & 63) == 0) wsum[t >> 6] = s;
    __syncthreads();
    if (t == 0) {
        float tot = wsum[0] + wsum[1] + wsum[2] + wsum[3];
        float r = 1.f / fmaxf(sqrtf(tot), 1e-12f);
        (which ? rk : rq)[row] = r;
    }
}

// ---------------- partial QK^T over an n-slice of 512 ----------------
__global__ __launch_bounds__(256) void k_qk_partial(const float* __restrict__ q,
    const float* __restrict__ kv, float* __restrict__ pS)
{
    int slice = blockIdx.x;
    int bh = blockIdx.y;
    int b = bh >> 2, h = bh & 3;
    __shared__ float qch[48][65];
    __shared__ float kch[48][65];
    float acc[3][3] = {{0.f}};
    int tid = threadIdx.x, dt = tid >> 4, et = tid & 15;
    const float* qbase = q + (size_t)(b * CCH + h * 48) * HWSZ;
    const float* kbase = kv + (size_t)(b * 384 + h * 48) * HWSZ;
    int n0s = slice * 512;
    for (int n0 = n0s; n0 < n0s + 512; n0 += 64) {
        for (int l = tid; l < 3072; l += 256) {
            int r = l >> 6, cc = l & 63;
            qch[r][cc] = qbase[(size_t)r * HWSZ + n0 + cc];
            kch[r][cc] = kbase[(size_t)r * HWSZ + n0 + cc];
        }
        __syncthreads();
#pragma unroll
        for (int nn = 0; nn < 64; ++nn) {
            float q0 = qch[dt][nn], q1 = qch[dt + 16][nn], q2 = qch[dt + 32][nn];
            float k0 = kch[et][nn], k1 = kch[et + 16][nn], k2 = kch[et + 32][nn];
            acc[0][0] += q0 * k0; acc[0][1] += q0 * k1; acc[0][2] += q0 * k2;
            acc[1][0] += q1 * k0; acc[1][1] += q1 * k1; acc[1][2] += q1 * k2;
            acc[2][0] += q2 * k0; acc[2][1] += q2 * k1; acc[2][2] += q2 * k2;
        }
        __syncthreads();
    }
    float* ps = pS + (size_t)(slice * 16 + bh) * 2304;
#pragma unroll
    for (int i = 0; i < 3; ++i)
#pragma unroll
        for (int j = 0; j < 3; ++j)
            ps[(dt + 16 * i) * 48 + (et + 16 * j)] = acc[i][j];
}

// ---------------- reduce partials, scale, softmax ----------------
__global__ __launch_bounds__(256) void k_attn_soft(const float* __restrict__ pS,
    const float* __restrict__ rq, const float* __restrict__ rk,
    const float* __restrict__ temp, float* __restrict__ attnw)
{
    int bh = blockIdx.x; int b = bh >> 2, h = bh & 3;
    __shared__ float S[48][49];
    int tid = threadIdx.x, dt = tid >> 4, et = tid & 15;
    float tv = temp[h];
#pragma unroll
    for (int i = 0; i < 3; ++i) {
#pragma unroll
        for (int j = 0; j < 3; ++j) {
            int d = dt + 16 * i, e = et + 16 * j;
            float s = 0.f;
            for (int sl = 0; sl < 32; ++sl)
                s += pS[(size_t)(sl * 16 + bh) * 2304 + d * 48 + e];
            S[d][e] = s * tv * rq[b * CCH + h * 48 + d] * rk[b * CCH + h * 48 + e];
        }
    }
    __syncthreads();
    if (tid < 48) {
        float mx = -1e30f;
        for (int e = 0; e < 48; ++e) mx = fmaxf(mx, S[tid][e]);
        float sum = 0.f;
        for (int e = 0; e < 48; ++e) sum += expf(S[tid][e] - mx);
        float inv = 1.f / sum;
        for (int e = 0; e < 48; ++e)
            attnw[((size_t)bh * 48 + tid) * 48 + e] = expf(S[tid][e] - mx) * inv;
    }
}

// ---------------- out = attn @ v -> transposed bf16 [b][px][192] ----------------
__global__ __launch_bounds__(256) void k_attn_v(const float* __restrict__ attnw,
    const float* __restrict__ kv, unsigned short* __restrict__ attoT)
{
    int px = blockIdx.x * 256 + threadIdx.x;
    int dg = blockIdx.y;
    int bh = blockIdx.z; int b = bh >> 2, h = bh & 3;
    __shared__ float aw[8][48];
    for (int l = threadIdx.x; l < 8 * 48; l += 256) {
        int i = l / 48, e = l - 48 * i;
        aw[i][e] = attnw[((size_t)bh * 48 + dg * 8 + i) * 48 + e];
    }
    __syncthreads();
    const float* vbase = kv + (size_t)(b * 384 + 192 + h * 48) * HWSZ + px;
    float acc[8] = {0.f};
#pragma unroll
    for (int e = 0; e < 48; ++e) {
        float vv = vbase[(size_t)e * HWSZ];
#pragma unroll
        for (int i = 0; i < 8; ++i) acc[i] += aw[i][e] * vv;
    }
    unsigned short* ob = attoT + ((size_t)b * HWSZ + px) * CCH + h * 48 + dg * 8;
    uint4 u;
    u.x = pk2(acc[0], acc[1]); u.y = pk2(acc[2], acc[3]);
    u.z = pk2(acc[4], acc[5]); u.w = pk2(acc[6], acc[7]);
    *(uint4*)ob = u;
}

// ---------------- gelu(y1)*y2 + transpose to [b][px][256] bf16 ----------------
__global__ __launch_bounds__(256) void k_gelutrans(const unsigned short* __restrict__ y1,
    const unsigned short* __restrict__ y2, unsigned short* __restrict__ gT)
{
    __shared__ unsigned short lt[64][264];
    int px0 = blockIdx.x * 64, b = blockIdx.z;
    for (int idx = threadIdx.x; idx < 2048; idx += 256) {
        int ch = idx >> 3, chunk = idx & 7;
        size_t base = ((size_t)(b * 256 + ch)) * HWSZ + px0 + chunk * 8;
        uint4 u1 = *(const uint4*)(y1 + base);
        uint4 u2 = *(const uint4*)(y2 + base);
        const unsigned short* p1 = (const unsigned short*)&u1;
        const unsigned short* p2 = (const unsigned short*)&u2;
#pragma unroll
        for (int i = 0; i < 8; ++i) {
            float a = b2f(p1[i]), v2 = b2f(p2[i]);
            float gl = 0.5f * a * (1.f + erff(a * 0.70710678118654752f)) * v2;
            lt[chunk * 8 + i][ch] = f2b(gl);
        }
    }
    __syncthreads();
    for (int idx = threadIdx.x; idx < 2048; idx += 256) {
        int px = idx >> 5, cc = idx & 31;
        *(uint4*)(gT + ((size_t)b * HWSZ + px0 + px) * 256 + cc * 8) = *(const uint4*)&lt[px][cc * 8];
    }
}

// ---------------- launcher ----------------
extern "C" void kernel_launch(void* const* d_in, const int* in_sizes, int n_in,
                              void* d_out, int out_size, void* d_ws, size_t ws_size,
                              hipStream_t stream)
{
    const float* x     = (const float*)d_in[0];
    const float* ln1g  = (const float*)d_in[1];
    const float* ln1b  = (const float*)d_in[2];
    const float* ln2g  = (const float*)d_in[3];
    const float* ln2b  = (const float*)d_in[4];
    const float* temp  = (const float*)d_in[5];
    const float* wqkv  = (const float*)d_in[6];
    const float* wqkvd = (const float*)d_in[7];
    const float* w5    = (const float*)d_in[8];
    const float* w7    = (const float*)d_in[9];
    const float* w9    = (const float*)d_in[10];
    const float* wattn = (const float*)d_in[11];
    const float* wffni = (const float*)d_in[12];
    const float* wffnd = (const float*)d_in[13];
    const float* wffno = (const float*)d_in[14];
    float* out = (float*)d_out;

    char* ws = (char*)d_ws;
    // arena
    unsigned short* xnT = (unsigned short*)(ws + 0);          // 25165824 (xnT, later xn2T)
    float* xn   = (float*)(ws + 25165824);                    // 50331648 (xn fp32; later kvtmp_half/attoT/y1r)
    float* q    = (float*)(ws + 75497472);                    // 50331648 (q; later y2r)
    float* kvr  = (float*)(ws + 125829120);                   // 100663296 (braw/bfilt early; kv; later y1d/y2d)
    float* braw = (float*)(ws + 125829120);
    float* bfilt = braw + 13381632 / 4;
    const size_t SM = 226492416;
    float* rq    = (float*)(ws + SM);
    float* rk    = (float*)(ws + SM + 4096);
    float* attnw = (float*)(ws + SM + 8192);                  // 147456
    float* pS    = (float*)(ws + SM + 155648);                // 4718592
    unsigned short* wq_b  = (unsigned short*)(ws + SM + 4874240);   // 147456
    unsigned short* wat_b = (unsigned short*)(ws + SM + 5021696);   // 73728
    unsigned short* wfi_b = (unsigned short*)(ws + SM + 5095424);   // 393216
    unsigned short* wfo_b = (unsigned short*)(ws + SM + 5488640);   // 196608
    const size_t NEED = SM + 5685248;
    if (ws_size < NEED) return;

    // phase reuse
    float* kvtmp_half = xn;
    unsigned short* attoT = (unsigned short*)xn;
    unsigned short* y1r = (unsigned short*)(ws + 25165824);
    unsigned short* y2r = (unsigned short*)(ws + 75497472);
    unsigned short* y1d = (unsigned short*)(ws + 125829120);
    unsigned short* y2d = (unsigned short*)(ws + 159383552);
    unsigned short* gT  = (unsigned short*)(ws + 192937984);

    dim3 blk(256);

    // 0. weights -> bf16 (padded)
    k_wconv<<<288, blk, 0, stream>>>(wqkv, wq_b, 384, 192, 192, 73728);
    k_wconv<<<144, blk, 0, stream>>>(wattn, wat_b, 192, 192, 192, 36864);
    k_wconv<<<384, blk, 0, stream>>>(wffni, wfi_b, 510, 192, 192, 98304);
    k_wconv<<<384, blk, 0, stream>>>(wffni + 510 * 192, wfi_b + 512 * 192, 510, 192, 192, 98304);
    k_wconv<<<384, blk, 0, stream>>>(wffno, wfo_b, 192, 510, 512, 98304);

    // 1. LN1 -> xn (fp32) + xnT (bf16 transposed)
    k_ln<1><<<256, blk, 0, stream>>>(x, ln1g, ln1b, xn, xnT);

    // 2. q = ssl(xn)
    for (int bd = 0; bd < 4; ++bd) {
        k_dwt<<<dim3(18, CCH, BB), blk, 0, stream>>>(xn, braw, bd);
        const float* wb = (bd <= 1) ? w5 : (bd == 2 ? w7 : w9);
        k_dwconv<<<dim3(18, CCH, BB), blk, 0, stream>>>(braw, wb, bfilt, 66, 66, CCH, 0, CCH, 0);
        k_idwt<<<dim3(64, CCH, BB), blk, 0, stream>>>(bfilt, q, bd);
    }

    // 3. kv = dw3x3(conv1x1(xn, w_qkv)) in 2 halves of 192 channels
    for (int h = 0; h < 2; ++h) {
        k_gemm<0, 0><<<dim3(64, 3, BB), blk, 0, stream>>>(xnT, wq_b + (size_t)h * 192 * 192,
                                                          kvtmp_half, nullptr, 192, 192, 192, 192);
        k_dwconv<<<dim3(64, 192, BB), blk, 0, stream>>>(kvtmp_half, wqkvd + (size_t)h * 192 * 9, kvr,
                                                        HEI, WID, 192, 0, 384, h * 192);
    }

    // 4. norms + attention
    k_rownorm<<<dim3(768, 2), blk, 0, stream>>>(q, kvr, rq, rk);
    k_qk_partial<<<dim3(32, 16), blk, 0, stream>>>(q, kvr, pS);
    k_attn_soft<<<16, blk, 0, stream>>>(pS, rq, rk, temp, attnw);
    k_attn_v<<<dim3(64, 6, 16), blk, 0, stream>>>(attnw, kvr, attoT);

    // 5. d_out = x + conv1x1(atto, w_attn_out)
    k_gemm<0, 1><<<dim3(64, 3, BB), blk, 0, stream>>>(attoT, wat_b, out, x, 192, 192, 192, 192);

    // 6. xn2T = LN2(d_out)
    k_ln<0><<<256, blk, 0, stream>>>(out, ln2g, ln2b, nullptr, xnT);

    // 7. GDFN in 2 hid-chunks of 256
    for (int ck = 0; ck < 2; ++ck) {
        int validc = (ck == 0) ? 256 : 254;
        k_gemm<1, 0><<<dim3(64, 4, BB), blk, 0, stream>>>(xnT, wfi_b + (size_t)(ck * 256) * 192,
                                                          y1r, nullptr, 192, 192, 192, 256);
        k_gemm<1, 0><<<dim3(64, 4, BB), blk, 0, stream>>>(xnT, wfi_b + (size_t)(512 + ck * 256) * 192,
                                                          y2r, nullptr, 192, 192, 192, 256);
        k_dwconv_b<<<dim3(64, 256, BB), blk, 0, stream>>>(y1r, wffnd + (size_t)(ck * 256) * 9, y1d, validc);
        k_dwconv_b<<<dim3(64, 256, BB), blk, 0, stream>>>(y2r, wffnd + (size_t)(510 + ck * 256) * 9, y2d, validc);
        k_gelutrans<<<dim3(256, 1, BB), blk, 0, stream>>>(y1d, y2d, gT);
        k_gemm<0, 1><<<dim3(64, 3, BB), blk, 0, stream>>>(gT, wfo_b + ck * 256, out, out, 256, 256, 512, 192);
    }
}

// Round 3
// 1343.229 us; speedup vs baseline: 4.7220x; 1.4516x over previous
//
#include <hip/hip_runtime.h>
#include <math.h>

#define HWSZ 16384
#define WID 128
#define HEI 128
#define CCH 192
#define BB 4

typedef short v8s __attribute__((ext_vector_type(8)));
typedef float f32x4 __attribute__((ext_vector_type(4)));

__device__ __constant__ float c_lo[6] = {0.035226291882100656f, -0.08544127388224149f, -0.13501102001039084f,
                                         0.4598775021193313f, 0.8068915093133388f, 0.3326705529509569f};
__device__ __constant__ float c_hi[6] = {-0.3326705529509569f, 0.8068915093133388f, -0.4598775021193313f,
                                         -0.13501102001039084f, 0.08544127388224149f, 0.035226291882100656f};

__device__ __forceinline__ float b2f(unsigned short h) { return __uint_as_float(((unsigned int)h) << 16); }
__device__ __forceinline__ unsigned short f2b(float f) {
    unsigned int u = __float_as_uint(f);
    return (unsigned short)((u + 0x7fffu + ((u >> 16) & 1u)) >> 16);
}
__device__ __forceinline__ unsigned int pk2(float a, float b) {
    return (unsigned int)f2b(a) | ((unsigned int)f2b(b) << 16);
}

// ---------------- weight fp32 -> bf16 with row/col zero-pad ----------------
__global__ __launch_bounds__(256) void k_wconv(const float* __restrict__ src,
    unsigned short* __restrict__ dst, int rows, int cols, int dcols, int total)
{
    int i = blockIdx.x * 256 + threadIdx.x;
    if (i >= total) return;
    int r = i / dcols, c = i - r * dcols;
    float v = (c < cols && r < rows) ? src[r * cols + c] : 0.f;
    dst[i] = f2b(v);
}

// ---------------- LayerNorm over channel dim; writes transposed bf16 (+opt fp32 spatial) ----------------
template<int WRITE_F32>
__global__ __launch_bounds__(256) void k_ln(const float* __restrict__ x,
    const float* __restrict__ g, const float* __restrict__ bta,
    float* __restrict__ xsp, unsigned short* __restrict__ xT)
{
    int pg = blockIdx.x * 256 + threadIdx.x;
    int b = pg >> 14, p = pg & 16383;
    const float* xp = x + (size_t)b * CCH * HWSZ + p;
    float s = 0.f, s2 = 0.f;
    for (int c = 0; c < CCH; ++c) {
        float v = xp[(size_t)c * HWSZ];
        s += v; s2 += v * v;
    }
    float mu = s * (1.f / CCH);
    float var = s2 * (1.f / CCH) - mu * mu;
    float rs = rsqrtf(var + 1e-5f);
    unsigned short* tr = xT + ((size_t)b * HWSZ + p) * CCH;
    float* sp = xsp + (size_t)b * CCH * HWSZ + p;
    for (int c0 = 0; c0 < CCH; c0 += 8) {
        float vv[8];
#pragma unroll
        for (int i = 0; i < 8; ++i) {
            float v = xp[(size_t)(c0 + i) * HWSZ];
            v = (v - mu) * rs * g[c0 + i] + bta[c0 + i];
            vv[i] = v;
            if (WRITE_F32) sp[(size_t)(c0 + i) * HWSZ] = v;
        }
        uint4 u;
        u.x = pk2(vv[0], vv[1]); u.y = pk2(vv[2], vv[3]);
        u.z = pk2(vv[4], vv[5]); u.w = pk2(vv[6], vv[7]);
        *(uint4*)(tr + c0) = u;
    }
}

// ---------------- bf16 MFMA GEMM ----------------
template<int OUT_BF16, int ADD>
__global__ __launch_bounds__(256) void k_gemm(
    const unsigned short* __restrict__ X, const unsigned short* __restrict__ W,
    void* __restrict__ outp, const float* __restrict__ addsrc,
    int K, int ldx, int ldw, int Mtot)
{
    int lane = threadIdx.x & 63, wv = threadIdx.x >> 6;
    int b = blockIdx.z;
    int r = lane & 15, koct = lane >> 4;
    int pxb = blockIdx.x * 256 + wv * 64;
    int co0 = blockIdx.y * 64;
    const unsigned short* xb = X + ((size_t)b * HWSZ + pxb + r) * ldx + koct * 8;
    const unsigned short* wb = W + (size_t)(co0 + r) * ldw + koct * 8;
    f32x4 z = {0.f, 0.f, 0.f, 0.f};
    f32x4 acc[4][4];
#pragma unroll
    for (int i = 0; i < 4; ++i)
#pragma unroll
        for (int j = 0; j < 4; ++j) acc[i][j] = z;

    for (int k0 = 0; k0 < K; k0 += 32) {
        v8s a0 = *(const v8s*)(wb + k0);
        v8s a1 = *(const v8s*)(wb + 16 * ldw + k0);
        v8s a2 = *(const v8s*)(wb + 32 * ldw + k0);
        v8s a3 = *(const v8s*)(wb + 48 * ldw + k0);
        v8s b0 = *(const v8s*)(xb + k0);
        v8s b1 = *(const v8s*)(xb + 16 * ldx + k0);
        v8s b2 = *(const v8s*)(xb + 32 * ldx + k0);
        v8s b3 = *(const v8s*)(xb + 48 * ldx + k0);
        acc[0][0] = __builtin_amdgcn_mfma_f32_16x16x32_bf16(a0, b0, acc[0][0], 0, 0, 0);
        acc[0][1] = __builtin_amdgcn_mfma_f32_16x16x32_bf16(a0, b1, acc[0][1], 0, 0, 0);
        acc[0][2] = __builtin_amdgcn_mfma_f32_16x16x32_bf16(a0, b2, acc[0][2], 0, 0, 0);
        acc[0][3] = __builtin_amdgcn_mfma_f32_16x16x32_bf16(a0, b3, acc[0][3], 0, 0, 0);
        acc[1][0] = __builtin_amdgcn_mfma_f32_16x16x32_bf16(a1, b0, acc[1][0], 0, 0, 0);
        acc[1][1] = __builtin_amdgcn_mfma_f32_16x16x32_bf16(a1, b1, acc[1][1], 0, 0, 0);
        acc[1][2] = __builtin_amdgcn_mfma_f32_16x16x32_bf16(a1, b2, acc[1][2], 0, 0, 0);
        acc[1][3] = __builtin_amdgcn_mfma_f32_16x16x32_bf16(a1, b3, acc[1][3], 0, 0, 0);
        acc[2][0] = __builtin_amdgcn_mfma_f32_16x16x32_bf16(a2, b0, acc[2][0], 0, 0, 0);
        acc[2][1] = __builtin_amdgcn_mfma_f32_16x16x32_bf16(a2, b1, acc[2][1], 0, 0, 0);
        acc[2][2] = __builtin_amdgcn_mfma_f32_16x16x32_bf16(a2, b2, acc[2][2], 0, 0, 0);
        acc[2][3] = __builtin_amdgcn_mfma_f32_16x16x32_bf16(a2, b3, acc[2][3], 0, 0, 0);
        acc[3][0] = __builtin_amdgcn_mfma_f32_16x16x32_bf16(a3, b0, acc[3][0], 0, 0, 0);
        acc[3][1] = __builtin_amdgcn_mfma_f32_16x16x32_bf16(a3, b1, acc[3][1], 0, 0, 0);
        acc[3][2] = __builtin_amdgcn_mfma_f32_16x16x32_bf16(a3, b2, acc[3][2], 0, 0, 0);
        acc[3][3] = __builtin_amdgcn_mfma_f32_16x16x32_bf16(a3, b3, acc[3][3], 0, 0, 0);
    }

    int row4 = koct * 4;
#pragma unroll
    for (int c = 0; c < 4; ++c) {
        int corow = co0 + c * 16 + row4;
#pragma unroll
        for (int nf = 0; nf < 4; ++nf) {
            int pxo = pxb + nf * 16 + r;
#pragma unroll
            for (int j = 0; j < 4; ++j) {
                size_t oi = ((size_t)b * Mtot + corow + j) * HWSZ + pxo;
                float v = acc[c][nf][j];
                if (ADD) v += addsrc[oi];
                if (OUT_BF16) ((unsigned short*)outp)[oi] = f2b(v);
                else ((float*)outp)[oi] = v;
            }
        }
    }
}

// ---------------- DWT row pass: xn[b][c][128][128] -> rowlo/rowhi [half][b][c][128][66] ----------------
__global__ __launch_bounds__(256) void k_dwt_row(const float* __restrict__ xn, float* __restrict__ rowbuf)
{
    int bc = blockIdx.x;
    const float* ip = xn + (size_t)bc * HWSZ;
    float* lo = rowbuf + (size_t)bc * 8448;
    float* hi = rowbuf + (size_t)(768 + bc) * 8448;
    for (int idx = threadIdx.x; idx < 128 * 66; idx += 256) {
        int row = idx / 66, ow = idx - row * 66;
        const float* rp = ip + row * 128;
        int base = 2 * ow - 4;
        float v[6];
#pragma unroll
        for (int j = 0; j < 6; ++j) {
            int iw = base + j;
            v[j] = (iw >= 0 && iw < 128) ? rp[iw] : 0.f;
        }
        float lv = 0.f, hv = 0.f;
#pragma unroll
        for (int j = 0; j < 6; ++j) {
            lv += v[j] * c_lo[5 - j];
            hv += v[j] * c_hi[5 - j];
        }
        lo[idx] = lv; hi[idx] = hv;
    }
}

// ---------------- DWT col pass + band 3x3 dwconv, 2 bands per block ----------------
__global__ __launch_bounds__(256) void k_dwt_colconv(const float* __restrict__ rowbuf,
    const float* __restrict__ w5, const float* __restrict__ w7, const float* __restrict__ w9,
    float* __restrict__ bfilt)
{
    __shared__ float rb[136][66];
    __shared__ float bnd[66][66];
    int h = blockIdx.x, c = blockIdx.y, b = blockIdx.z;
    int bc = b * CCH + c;
    const float* src = rowbuf + (size_t)(h * 768 + bc) * 8448;
    for (int i = threadIdx.x; i < 136 * 66; i += 256) {
        int r = i / 66, cc = i - r * 66;
        rb[r][cc] = (r >= 4 && r < 132) ? src[(r - 4) * 66 + cc] : 0.f;
    }
    for (int fs = 0; fs < 2; ++fs) {
        __syncthreads();
        int band = fs * 2 + h;
        const float* fa = fs ? c_hi : c_lo;
        for (int i = threadIdx.x; i < 4356; i += 256) {
            int oh = i / 66, ow = i - oh * 66;
            float a = 0.f;
#pragma unroll
            for (int ki = 0; ki < 6; ++ki)
                a += fa[5 - ki] * rb[oh * 2 + ki][ow];
            bnd[oh][ow] = a;
        }
        __syncthreads();
        const float* wsel = (band < 2) ? w5 : (band == 2 ? w7 : w9);
        float wr[9];
#pragma unroll
        for (int j = 0; j < 9; ++j) wr[j] = wsel[c * 9 + j];
        float* op = bfilt + ((size_t)bc * 4 + band) * 4356;
        for (int i = threadIdx.x; i < 4356; i += 256) {
            int y = i / 66, xx = i - y * 66;
            float a = 0.f;
#pragma unroll
            for (int dy = 0; dy < 3; ++dy) {
                int yy = y + dy - 1;
                if (yy < 0 || yy >= 66) continue;
#pragma unroll
                for (int dx = 0; dx < 3; ++dx) {
                    int x2 = xx + dx - 1;
                    if (x2 < 0 || x2 >= 66) continue;
                    a += bnd[yy][x2] * wr[dy * 3 + dx];
                }
            }
            op[i] = a;
        }
    }
}

// ---------------- fused IDWT over 4 bands -> q bf16, + fused sum(q^2) ----------------
__global__ __launch_bounds__(256) void k_idwt_fused(const float* __restrict__ bfilt,
    unsigned short* __restrict__ q, float* __restrict__ rq2)
{
    __shared__ float L[4][3][66];
    __shared__ float w4s[4];
    int T = blockIdx.x;      // 0..63 -> rows 2T, 2T+1
    int c = blockIdx.y, b = blockIdx.z;
    int bc = b * CCH + c;
    const float* bp = bfilt + (size_t)bc * 4 * 4356;
    for (int i = threadIdx.x; i < 4 * 3 * 66; i += 256) {
        int band = i / 198, rem = i - band * 198;
        int rr = rem / 66, cc = rem - rr * 66;
        L[band][rr][cc] = bp[band * 4356 + (T + rr) * 66 + cc];
    }
    __syncthreads();
    int oh = T * 2 + (threadIdx.x >> 7), ow = threadIdx.x & 127;
    int m = ow >> 1;
    int pr = oh & 1, pc = ow & 1;
    float fal[3], fah[3], fbl[3], fbh[3];
#pragma unroll
    for (int i = 0; i < 3; ++i) {
        fal[i] = c_lo[2 * i + 1 - pr]; fah[i] = c_hi[2 * i + 1 - pr];
        fbl[i] = c_lo[2 * i + 1 - pc]; fbh[i] = c_hi[2 * i + 1 - pc];
    }
    float acc = 0.f;
#pragma unroll
    for (int band = 0; band < 4; ++band) {
#pragma unroll
        for (int i = 0; i < 3; ++i) {
            float b0 = L[band][i][m], b1 = L[band][i][m + 1], b2 = L[band][i][m + 2];
            float rs = (band & 1) ? (fbh[0] * b0 + fbh[1] * b1 + fbh[2] * b2)
                                  : (fbl[0] * b0 + fbl[1] * b1 + fbl[2] * b2);
            acc += ((band < 2) ? fal[i] : fah[i]) * rs;
        }
    }
    q[(size_t)bc * HWSZ + oh * WID + ow] = f2b(acc);
    float s = acc * acc;
    for (int off = 32; off; off >>= 1) s += __shfl_down(s, off, 64);
    if ((threadIdx.x & 63) == 0) w4s[threadIdx.x >> 6] = s;
    __syncthreads();
    if (threadIdx.x == 0) atomicAdd(rq2 + bc, w4s[0] + w4s[1] + w4s[2] + w4s[3]);
}

// ---------------- depthwise 3x3 bf16 for kv path + fused sum(k^2) ----------------
__global__ __launch_bounds__(256) void k_dwconv_kv(const unsigned short* __restrict__ in,
    const float* __restrict__ w, unsigned short* __restrict__ kv, float* __restrict__ rk2, int half)
{
    int p = blockIdx.x * 256 + threadIdx.x;
    int c = blockIdx.y, b = blockIdx.z;
    int y = p >> 7, xq = p & 127;
    const unsigned short* ip = in + (size_t)(b * CCH + c) * HWSZ;
    float wr[9];
#pragma unroll
    for (int j = 0; j < 9; ++j) wr[j] = w[c * 9 + j];
    float acc = 0.f;
#pragma unroll
    for (int dy = 0; dy < 3; ++dy) {
        int yy = y + dy - 1;
        if (yy < 0 || yy >= HEI) continue;
#pragma unroll
        for (int dx = 0; dx < 3; ++dx) {
            int xx = xq + dx - 1;
            if (xx < 0 || xx >= WID) continue;
            acc += b2f(ip[yy * WID + xx]) * wr[dy * 3 + dx];
        }
    }
    kv[(size_t)(b * 384 + half * CCH + c) * HWSZ + p] = f2b(acc);
    if (half == 0) {
        __shared__ float w4s[4];
        float s = acc * acc;
        for (int off = 32; off; off >>= 1) s += __shfl_down(s, off, 64);
        if ((threadIdx.x & 63) == 0) w4s[threadIdx.x >> 6] = s;
        __syncthreads();
        if (threadIdx.x == 0) atomicAdd(rk2 + b * CCH + c, w4s[0] + w4s[1] + w4s[2] + w4s[3]);
    }
}

// ---------------- finalize norms ----------------
__global__ __launch_bounds__(256) void k_fnorm(const float* __restrict__ rq2,
    const float* __restrict__ rk2, float* __restrict__ rq, float* __restrict__ rk)
{
    int i = blockIdx.x * 256 + threadIdx.x;
    if (i < 768) rq[i] = 1.f / fmaxf(sqrtf(rq2[i]), 1e-12f);
    else if (i < 1536) rk[i - 768] = 1.f / fmaxf(sqrtf(rk2[i - 768]), 1e-12f);
}

// ---------------- depthwise 3x3 bf16 (FFN path), Ctot=256 ----------------
__global__ __launch_bounds__(256) void k_dwconv_b(const unsigned short* __restrict__ in,
    const float* __restrict__ w, unsigned short* __restrict__ out, int validc)
{
    int p = blockIdx.x * 256 + threadIdx.x;
    int c = blockIdx.y, b = blockIdx.z;
    size_t obase = ((size_t)(b * 256 + c)) * HWSZ + p;
    if (c >= validc) { out[obase] = 0; return; }
    int y = p >> 7, xq = p & 127;
    const unsigned short* ip = in + ((size_t)(b * 256 + c)) * HWSZ;
    float wr[9];
#pragma unroll
    for (int j = 0; j < 9; ++j) wr[j] = w[c * 9 + j];
    float acc = 0.f;
#pragma unroll
    for (int dy = 0; dy < 3; ++dy) {
        int yy = y + dy - 1;
        if (yy < 0 || yy >= HEI) continue;
#pragma unroll
        for (int dx = 0; dx < 3; ++dx) {
            int xx = xq + dx - 1;
            if (xx < 0 || xx >= WID) continue;
            acc += b2f(ip[yy * WID + xx]) * wr[dy * 3 + dx];
        }
    }
    out[obase] = f2b(acc);
}

// ---------------- partial QK^T over an n-slice of 1024 (bf16 inputs) ----------------
__global__ __launch_bounds__(256) void k_qk_partial(const unsigned short* __restrict__ q,
    const unsigned short* __restrict__ kv, float* __restrict__ pS)
{
    int slice = blockIdx.x;   // 0..15
    int bh = blockIdx.y;      // 0..15
    int b = bh >> 2, h = bh & 3;
    __shared__ float qch[48][65];
    __shared__ float kch[48][65];
    float acc[3][3] = {{0.f}};
    int tid = threadIdx.x, dt = tid >> 4, et = tid & 15;
    const unsigned short* qbase = q + (size_t)(b * CCH + h * 48) * HWSZ;
    const unsigned short* kbase = kv + (size_t)(b * 384 + h * 48) * HWSZ;
    int n0s = slice * 1024;
    for (int n0 = n0s; n0 < n0s + 1024; n0 += 64) {
        for (int l = tid; l < 3072; l += 256) {
            int r = l >> 6, cc = l & 63;
            qch[r][cc] = b2f(qbase[(size_t)r * HWSZ + n0 + cc]);
            kch[r][cc] = b2f(kbase[(size_t)r * HWSZ + n0 + cc]);
        }
        __syncthreads();
#pragma unroll
        for (int nn = 0; nn < 64; ++nn) {
            float q0 = qch[dt][nn], q1 = qch[dt + 16][nn], q2 = qch[dt + 32][nn];
            float k0 = kch[et][nn], k1 = kch[et + 16][nn], k2 = kch[et + 32][nn];
            acc[0][0] += q0 * k0; acc[0][1] += q0 * k1; acc[0][2] += q0 * k2;
            acc[1][0] += q1 * k0; acc[1][1] += q1 * k1; acc[1][2] += q1 * k2;
            acc[2][0] += q2 * k0; acc[2][1] += q2 * k1; acc[2][2] += q2 * k2;
        }
        __syncthreads();
    }
    float* ps = pS + (size_t)(slice * 16 + bh) * 2304;
#pragma unroll
    for (int i = 0; i < 3; ++i)
#pragma unroll
        for (int j = 0; j < 3; ++j)
            ps[(dt + 16 * i) * 48 + (et + 16 * j)] = acc[i][j];
}

// ---------------- reduce partials, scale, softmax ----------------
__global__ __launch_bounds__(256) void k_attn_soft(const float* __restrict__ pS,
    const float* __restrict__ rq, const float* __restrict__ rk,
    const float* __restrict__ temp, float* __restrict__ attnw)
{
    int bh = blockIdx.x; int b = bh >> 2, h = bh & 3;
    __shared__ float S[48][49];
    int tid = threadIdx.x, dt = tid >> 4, et = tid & 15;
    float tv = temp[h];
#pragma unroll
    for (int i = 0; i < 3; ++i) {
#pragma unroll
        for (int j = 0; j < 3; ++j) {
            int d = dt + 16 * i, e = et + 16 * j;
            float s = 0.f;
            for (int sl = 0; sl < 16; ++sl)
                s += pS[(size_t)(sl * 16 + bh) * 2304 + d * 48 + e];
            S[d][e] = s * tv * rq[b * CCH + h * 48 + d] * rk[b * CCH + h * 48 + e];
        }
    }
    __syncthreads();
    if (tid < 48) {
        float mx = -1e30f;
        for (int e = 0; e < 48; ++e) mx = fmaxf(mx, S[tid][e]);
        float sum = 0.f;
        for (int e = 0; e < 48; ++e) sum += expf(S[tid][e] - mx);
        float inv = 1.f / sum;
        for (int e = 0; e < 48; ++e)
            attnw[((size_t)bh * 48 + tid) * 48 + e] = expf(S[tid][e] - mx) * inv;
    }
}

// ---------------- out = attn @ v -> transposed bf16 [b][px][192] ----------------
__global__ __launch_bounds__(256) void k_attn_v(const float* __restrict__ attnw,
    const unsigned short* __restrict__ kv, unsigned short* __restrict__ attoT)
{
    int px = blockIdx.x * 256 + threadIdx.x;
    int dg = blockIdx.y;
    int bh = blockIdx.z; int b = bh >> 2, h = bh & 3;
    __shared__ float aw[8][48];
    for (int l = threadIdx.x; l < 8 * 48; l += 256) {
        int i = l / 48, e = l - 48 * i;
        aw[i][e] = attnw[((size_t)bh * 48 + dg * 8 + i) * 48 + e];
    }
    __syncthreads();
    const unsigned short* vbase = kv + (size_t)(b * 384 + 192 + h * 48) * HWSZ + px;
    float acc[8] = {0.f};
#pragma unroll
    for (int e = 0; e < 48; ++e) {
        float vv = b2f(vbase[(size_t)e * HWSZ]);
#pragma unroll
        for (int i = 0; i < 8; ++i) acc[i] += aw[i][e] * vv;
    }
    unsigned short* ob = attoT + ((size_t)b * HWSZ + px) * CCH + h * 48 + dg * 8;
    uint4 u;
    u.x = pk2(acc[0], acc[1]); u.y = pk2(acc[2], acc[3]);
    u.z = pk2(acc[4], acc[5]); u.w = pk2(acc[6], acc[7]);
    *(uint4*)ob = u;
}

// ---------------- gelu(y1)*y2 + transpose to [b][px][256] bf16 ----------------
__global__ __launch_bounds__(256) void k_gelutrans(const unsigned short* __restrict__ y1,
    const unsigned short* __restrict__ y2, unsigned short* __restrict__ gT)
{
    __shared__ unsigned short lt[64][264];
    int px0 = blockIdx.x * 64, b = blockIdx.z;
    for (int idx = threadIdx.x; idx < 2048; idx += 256) {
        int ch = idx >> 3, chunk = idx & 7;
        size_t base = ((size_t)(b * 256 + ch)) * HWSZ + px0 + chunk * 8;
        uint4 u1 = *(const uint4*)(y1 + base);
        uint4 u2 = *(const uint4*)(y2 + base);
        const unsigned short* p1 = (const unsigned short*)&u1;
        const unsigned short* p2 = (const unsigned short*)&u2;
#pragma unroll
        for (int i = 0; i < 8; ++i) {
            float a = b2f(p1[i]), v2 = b2f(p2[i]);
            float gl = 0.5f * a * (1.f + erff(a * 0.70710678118654752f)) * v2;
            lt[chunk * 8 + i][ch] = f2b(gl);
        }
    }
    __syncthreads();
    for (int idx = threadIdx.x; idx < 2048; idx += 256) {
        int px = idx >> 5, cc = idx & 31;
        *(uint4*)(gT + ((size_t)b * HWSZ + px0 + px) * 256 + cc * 8) = *(const uint4*)&lt[px][cc * 8];
    }
}

// ---------------- launcher ----------------
extern "C" void kernel_launch(void* const* d_in, const int* in_sizes, int n_in,
                              void* d_out, int out_size, void* d_ws, size_t ws_size,
                              hipStream_t stream)
{
    const float* x     = (const float*)d_in[0];
    const float* ln1g  = (const float*)d_in[1];
    const float* ln1b  = (const float*)d_in[2];
    const float* ln2g  = (const float*)d_in[3];
    const float* ln2b  = (const float*)d_in[4];
    const float* temp  = (const float*)d_in[5];
    const float* wqkv  = (const float*)d_in[6];
    const float* wqkvd = (const float*)d_in[7];
    const float* w5    = (const float*)d_in[8];
    const float* w7    = (const float*)d_in[9];
    const float* w9    = (const float*)d_in[10];
    const float* wattn = (const float*)d_in[11];
    const float* wffni = (const float*)d_in[12];
    const float* wffnd = (const float*)d_in[13];
    const float* wffno = (const float*)d_in[14];
    float* out = (float*)d_out;

    char* ws = (char*)d_ws;
    // arena
    unsigned short* xnT = (unsigned short*)(ws + 0);              // 25.2MB (later xn2T)
    float* xn   = (float*)(ws + 25165824);                        // 50.3MB fp32 (later kvtmp/attoT/y1r)
    unsigned short* q = (unsigned short*)(ws + 75497472);         // 25.2MB bf16 (later y2r)
    unsigned short* kvb = (unsigned short*)(ws + 100663296);      // 50.3MB bf16 kv (bfilt earlier; later y1d)
    float* bfilt = (float*)(ws + 100663296);                      // 53.5MB
    float* rowbuf = (float*)(ws + 154189824);                     // 51.9MB -> ends 206094336
    const size_t SM = 226492416;
    float* rq2   = (float*)(ws + SM);
    float* rk2   = (float*)(ws + SM + 4096);
    float* rq    = (float*)(ws + SM + 8192);
    float* rk    = (float*)(ws + SM + 12288);
    float* pS    = (float*)(ws + SM + 16384);                     // 2359296, aliased by attnw
    float* attnw = pS;
    unsigned short* wq_b  = (unsigned short*)(ws + SM + 2375680); // 147456
    unsigned short* wat_b = (unsigned short*)(ws + SM + 2523136); // 73728
    unsigned short* wfi_b = (unsigned short*)(ws + SM + 2596864); // 393216
    unsigned short* wfo_b = (unsigned short*)(ws + SM + 2990080); // 196608
    const size_t NEED = SM + 3186688;
    if (ws_size < NEED) return;

    // phase reuse
    unsigned short* kvtmp = (unsigned short*)xn;
    unsigned short* attoT = (unsigned short*)xn;
    unsigned short* y1r = (unsigned short*)(ws + 25165824);
    unsigned short* y2r = (unsigned short*)(ws + 75497472);
    unsigned short* y1d = (unsigned short*)(ws + 125829120);
    unsigned short* y2d = (unsigned short*)(ws + 159383552);
    unsigned short* gT  = (unsigned short*)(ws + 192937984);

    dim3 blk(256);

    // 0. weights -> bf16 (padded); zero norm accumulators
    hipMemsetAsync(ws + SM, 0, 8192, stream);
    k_wconv<<<288, blk, 0, stream>>>(wqkv, wq_b, 384, 192, 192, 73728);
    k_wconv<<<144, blk, 0, stream>>>(wattn, wat_b, 192, 192, 192, 36864);
    k_wconv<<<384, blk, 0, stream>>>(wffni, wfi_b, 510, 192, 192, 98304);
    k_wconv<<<384, blk, 0, stream>>>(wffni + 510 * 192, wfi_b + 512 * 192, 510, 192, 192, 98304);
    k_wconv<<<384, blk, 0, stream>>>(wffno, wfo_b, 192, 510, 512, 98304);

    // 1. LN1 -> xn fp32 + xnT bf16
    k_ln<1><<<256, blk, 0, stream>>>(x, ln1g, ln1b, xn, xnT);

    // 2. SSL: row dwt -> col dwt + band conv -> fused idwt (writes q bf16 + q^2 sums)
    k_dwt_row<<<768, blk, 0, stream>>>(xn, rowbuf);
    k_dwt_colconv<<<dim3(2, CCH, BB), blk, 0, stream>>>(rowbuf, w5, w7, w9, bfilt);
    k_idwt_fused<<<dim3(64, CCH, BB), blk, 0, stream>>>(bfilt, q, rq2);

    // 3. kv = dw3x3(conv1x1(xn, w_qkv)) bf16, k^2 sums fused on half 0
    for (int h = 0; h < 2; ++h) {
        k_gemm<1, 0><<<dim3(64, 3, BB), blk, 0, stream>>>(xnT, wq_b + (size_t)h * 192 * 192,
                                                          kvtmp, nullptr, 192, 192, 192, 192);
        k_dwconv_kv<<<dim3(64, 192, BB), blk, 0, stream>>>(kvtmp, wqkvd + (size_t)h * 192 * 9,
                                                           kvb, rk2, h);
    }

    // 4. norms + attention
    k_fnorm<<<6, blk, 0, stream>>>(rq2, rk2, rq, rk);
    k_qk_partial<<<dim3(16, 16), blk, 0, stream>>>(q, kvb, pS);
    k_attn_soft<<<16, blk, 0, stream>>>(pS, rq, rk, temp, attnw);
    k_attn_v<<<dim3(64, 6, 16), blk, 0, stream>>>(attnw, kvb, attoT);

    // 5. d_out = x + conv1x1(atto, w_attn_out)
    k_gemm<0, 1><<<dim3(64, 3, BB), blk, 0, stream>>>(attoT, wat_b, out, x, 192, 192, 192, 192);

    // 6. xn2T = LN2(d_out)
    k_ln<0><<<256, blk, 0, stream>>>(out, ln2g, ln2b, nullptr, xnT);

    // 7. GDFN in 2 hid-chunks of 256
    for (int ck = 0; ck < 2; ++ck) {
        int validc = (ck == 0) ? 256 : 254;
        k_gemm<1, 0><<<dim3(64, 4, BB), blk, 0, stream>>>(xnT, wfi_b + (size_t)(ck * 256) * 192,
                                                          y1r, nullptr, 192, 192, 192, 256);
        k_gemm<1, 0><<<dim3(64, 4, BB), blk, 0, stream>>>(xnT, wfi_b + (size_t)(512 + ck * 256) * 192,
                                                          y2r, nullptr, 192, 192, 192, 256);
        k_dwconv_b<<<dim3(64, 256, BB), blk, 0, stream>>>(y1r, wffnd + (size_t)(ck * 256) * 9, y1d, validc);
        k_dwconv_b<<<dim3(64, 256, BB), blk, 0, stream>>>(y2r, wffnd + (size_t)(510 + ck * 256) * 9, y2d, validc);
        k_gelutrans<<<dim3(256, 1, BB), blk, 0, stream>>>(y1d, y2d, gT);
        k_gemm<0, 1><<<dim3(64, 3, BB), blk, 0, stream>>>(gT, wfo_b + ck * 256, out, out, 256, 256, 512, 192);
    }
}

// Round 4
// 826.746 us; speedup vs baseline: 7.6720x; 1.6247x over previous
//
#include <hip/hip_runtime.h>
#include <math.h>

#define HWSZ 16384
#define WID 128
#define HEI 128
#define CCH 192
#define BB 4

typedef short v8s __attribute__((ext_vector_type(8)));
typedef float f32x4 __attribute__((ext_vector_type(4)));

__device__ __constant__ float c_lo[6] = {0.035226291882100656f, -0.08544127388224149f, -0.13501102001039084f,
                                         0.4598775021193313f, 0.8068915093133388f, 0.3326705529509569f};
__device__ __constant__ float c_hi[6] = {-0.3326705529509569f, 0.8068915093133388f, -0.4598775021193313f,
                                         -0.13501102001039084f, 0.08544127388224149f, 0.035226291882100656f};

__device__ __forceinline__ float b2f(unsigned short h) { return __uint_as_float(((unsigned int)h) << 16); }
__device__ __forceinline__ unsigned short f2b(float f) {
    unsigned int u = __float_as_uint(f);
    return (unsigned short)((u + 0x7fffu + ((u >> 16) & 1u)) >> 16);
}
__device__ __forceinline__ unsigned int pk2(float a, float b) {
    return (unsigned int)f2b(a) | ((unsigned int)f2b(b) << 16);
}

// ---------------- weight fp32 -> bf16 with row/col zero-pad ----------------
__global__ __launch_bounds__(256) void k_wconv(const float* __restrict__ src,
    unsigned short* __restrict__ dst, int rows, int cols, int dcols, int total)
{
    int i = blockIdx.x * 256 + threadIdx.x;
    if (i >= total) return;
    int r = i / dcols, c = i - r * dcols;
    float v = (c < cols && r < rows) ? src[r * cols + c] : 0.f;
    dst[i] = f2b(v);
}

// ---------------- LayerNorm over channel dim; writes transposed bf16 (+opt fp32 spatial) ----------------
template<int WRITE_F32>
__global__ __launch_bounds__(256) void k_ln(const float* __restrict__ x,
    const float* __restrict__ g, const float* __restrict__ bta,
    float* __restrict__ xsp, unsigned short* __restrict__ xT)
{
    int pg = blockIdx.x * 256 + threadIdx.x;
    int b = pg >> 14, p = pg & 16383;
    const float* xp = x + (size_t)b * CCH * HWSZ + p;
    float s = 0.f, s2 = 0.f;
    for (int c = 0; c < CCH; ++c) {
        float v = xp[(size_t)c * HWSZ];
        s += v; s2 += v * v;
    }
    float mu = s * (1.f / CCH);
    float var = s2 * (1.f / CCH) - mu * mu;
    float rs = rsqrtf(var + 1e-5f);
    unsigned short* tr = xT + ((size_t)b * HWSZ + p) * CCH;
    float* sp = xsp + (size_t)b * CCH * HWSZ + p;
    for (int c0 = 0; c0 < CCH; c0 += 8) {
        float vv[8];
#pragma unroll
        for (int i = 0; i < 8; ++i) {
            float v = xp[(size_t)(c0 + i) * HWSZ];
            v = (v - mu) * rs * g[c0 + i] + bta[c0 + i];
            vv[i] = v;
            if (WRITE_F32) sp[(size_t)(c0 + i) * HWSZ] = v;
        }
        uint4 u;
        u.x = pk2(vv[0], vv[1]); u.y = pk2(vv[2], vv[3]);
        u.z = pk2(vv[4], vv[5]); u.w = pk2(vv[6], vv[7]);
        *(uint4*)(tr + c0) = u;
    }
}

// ---------------- bf16 MFMA GEMM ----------------
template<int OUT_BF16, int ADD>
__global__ __launch_bounds__(256) void k_gemm(
    const unsigned short* __restrict__ X, const unsigned short* __restrict__ W,
    void* __restrict__ outp, const float* __restrict__ addsrc,
    int K, int ldx, int ldw, int Mtot)
{
    int lane = threadIdx.x & 63, wv = threadIdx.x >> 6;
    int b = blockIdx.z;
    int r = lane & 15, koct = lane >> 4;
    int pxb = blockIdx.x * 256 + wv * 64;
    int co0 = blockIdx.y * 64;
    const unsigned short* xb = X + ((size_t)b * HWSZ + pxb + r) * ldx + koct * 8;
    const unsigned short* wb = W + (size_t)(co0 + r) * ldw + koct * 8;
    f32x4 z = {0.f, 0.f, 0.f, 0.f};
    f32x4 acc[4][4];
#pragma unroll
    for (int i = 0; i < 4; ++i)
#pragma unroll
        for (int j = 0; j < 4; ++j) acc[i][j] = z;

    for (int k0 = 0; k0 < K; k0 += 32) {
        v8s a0 = *(const v8s*)(wb + k0);
        v8s a1 = *(const v8s*)(wb + 16 * ldw + k0);
        v8s a2 = *(const v8s*)(wb + 32 * ldw + k0);
        v8s a3 = *(const v8s*)(wb + 48 * ldw + k0);
        v8s b0 = *(const v8s*)(xb + k0);
        v8s b1 = *(const v8s*)(xb + 16 * ldx + k0);
        v8s b2 = *(const v8s*)(xb + 32 * ldx + k0);
        v8s b3 = *(const v8s*)(xb + 48 * ldx + k0);
        acc[0][0] = __builtin_amdgcn_mfma_f32_16x16x32_bf16(a0, b0, acc[0][0], 0, 0, 0);
        acc[0][1] = __builtin_amdgcn_mfma_f32_16x16x32_bf16(a0, b1, acc[0][1], 0, 0, 0);
        acc[0][2] = __builtin_amdgcn_mfma_f32_16x16x32_bf16(a0, b2, acc[0][2], 0, 0, 0);
        acc[0][3] = __builtin_amdgcn_mfma_f32_16x16x32_bf16(a0, b3, acc[0][3], 0, 0, 0);
        acc[1][0] = __builtin_amdgcn_mfma_f32_16x16x32_bf16(a1, b0, acc[1][0], 0, 0, 0);
        acc[1][1] = __builtin_amdgcn_mfma_f32_16x16x32_bf16(a1, b1, acc[1][1], 0, 0, 0);
        acc[1][2] = __builtin_amdgcn_mfma_f32_16x16x32_bf16(a1, b2, acc[1][2], 0, 0, 0);
        acc[1][3] = __builtin_amdgcn_mfma_f32_16x16x32_bf16(a1, b3, acc[1][3], 0, 0, 0);
        acc[2][0] = __builtin_amdgcn_mfma_f32_16x16x32_bf16(a2, b0, acc[2][0], 0, 0, 0);
        acc[2][1] = __builtin_amdgcn_mfma_f32_16x16x32_bf16(a2, b1, acc[2][1], 0, 0, 0);
        acc[2][2] = __builtin_amdgcn_mfma_f32_16x16x32_bf16(a2, b2, acc[2][2], 0, 0, 0);
        acc[2][3] = __builtin_amdgcn_mfma_f32_16x16x32_bf16(a2, b3, acc[2][3], 0, 0, 0);
        acc[3][0] = __builtin_amdgcn_mfma_f32_16x16x32_bf16(a3, b0, acc[3][0], 0, 0, 0);
        acc[3][1] = __builtin_amdgcn_mfma_f32_16x16x32_bf16(a3, b1, acc[3][1], 0, 0, 0);
        acc[3][2] = __builtin_amdgcn_mfma_f32_16x16x32_bf16(a3, b2, acc[3][2], 0, 0, 0);
        acc[3][3] = __builtin_amdgcn_mfma_f32_16x16x32_bf16(a3, b3, acc[3][3], 0, 0, 0);
    }

    int row4 = koct * 4;
#pragma unroll
    for (int c = 0; c < 4; ++c) {
        int corow = co0 + c * 16 + row4;
#pragma unroll
        for (int nf = 0; nf < 4; ++nf) {
            int pxo = pxb + nf * 16 + r;
#pragma unroll
            for (int j = 0; j < 4; ++j) {
                size_t oi = ((size_t)b * Mtot + corow + j) * HWSZ + pxo;
                float v = acc[c][nf][j];
                if (ADD) v += addsrc[oi];
                if (OUT_BF16) ((unsigned short*)outp)[oi] = f2b(v);
                else ((float*)outp)[oi] = v;
            }
        }
    }
}

// ---------------- depthwise helpers ----------------
__device__ __forceinline__ void dw_load_tile(const unsigned short* __restrict__ ip,
    int r0, float (&tile)[18][132], int tid)
{
    for (int e = tid; e < 576; e += 256) {      // 18 rows x 32 uint2
        int r = e >> 5, q4 = e & 31;
        int gr = r0 - 1 + r;
        float v0 = 0.f, v1 = 0.f, v2 = 0.f, v3 = 0.f;
        if (gr >= 0 && gr < HEI) {
            uint2 u = *(const uint2*)(ip + gr * WID + q4 * 4);
            const unsigned short* pu = (const unsigned short*)&u;
            v0 = b2f(pu[0]); v1 = b2f(pu[1]); v2 = b2f(pu[2]); v3 = b2f(pu[3]);
        }
        int cb = 1 + q4 * 4;
        tile[r][cb] = v0; tile[r][cb + 1] = v1; tile[r][cb + 2] = v2; tile[r][cb + 3] = v3;
    }
    if (tid < 18) { tile[tid][0] = 0.f; tile[tid][129] = 0.f; }
}

__device__ __forceinline__ void dw_compute8(const float (&tile)[18][132],
    const float* wr, int rl, int px0, float (&o)[8])
{
    float r0[10], r1[10], r2[10];
#pragma unroll
    for (int i = 0; i < 10; ++i) {
        r0[i] = tile[rl][px0 + i];
        r1[i] = tile[rl + 1][px0 + i];
        r2[i] = tile[rl + 2][px0 + i];
    }
#pragma unroll
    for (int j = 0; j < 8; ++j) {
        o[j] = r0[j] * wr[0] + r0[j + 1] * wr[1] + r0[j + 2] * wr[2]
             + r1[j] * wr[3] + r1[j + 1] * wr[4] + r1[j + 2] * wr[5]
             + r2[j] * wr[6] + r2[j + 1] * wr[7] + r2[j + 2] * wr[8];
    }
}

// ---------------- depthwise 3x3 bf16, 16 rows/block, 8px/thread; opt k^2 reduce ----------------
template<int REDUCE>
__global__ __launch_bounds__(256) void k_dw8(const unsigned short* __restrict__ in,
    const float* __restrict__ w, unsigned short* __restrict__ out, float* __restrict__ red,
    int inCtot, int inCoff, int outCtot, int outCoff)
{
    __shared__ float tile[18][132];
    int g = blockIdx.x, c = blockIdx.y, b = blockIdx.z;
    int tid = threadIdx.x;
    const unsigned short* ip = in + (size_t)(b * inCtot + inCoff + c) * HWSZ;
    dw_load_tile(ip, g * 16, tile, tid);
    float wr[9];
#pragma unroll
    for (int j = 0; j < 9; ++j) wr[j] = w[c * 9 + j];
    __syncthreads();
    int rl = tid >> 4, px0 = (tid & 15) * 8;
    float o[8];
    dw_compute8(tile, wr, rl, px0, o);
    unsigned short* op = out + (size_t)(b * outCtot + outCoff + c) * HWSZ + (g * 16 + rl) * WID + px0;
    uint4 u;
    u.x = pk2(o[0], o[1]); u.y = pk2(o[2], o[3]); u.z = pk2(o[4], o[5]); u.w = pk2(o[6], o[7]);
    *(uint4*)op = u;
    if (REDUCE) {
        float s = 0.f;
#pragma unroll
        for (int j = 0; j < 8; ++j) s += o[j] * o[j];
        for (int off = 32; off; off >>= 1) s += __shfl_down(s, off, 64);
        __shared__ float w4[4];
        if ((tid & 63) == 0) w4[tid >> 6] = s;
        __syncthreads();
        if (tid == 0) atomicAdd(red + b * CCH + c, w4[0] + w4[1] + w4[2] + w4[3]);
    }
}

// ---------------- fused FFN: dw3x3(y1), dw3x3(y2), gelu(a)*b -> bf16 channel-major ----------------
__global__ __launch_bounds__(256) void k_dw8gate(const unsigned short* __restrict__ in1,
    const unsigned short* __restrict__ in2, const float* __restrict__ w1,
    const float* __restrict__ w2, unsigned short* __restrict__ out, int validc)
{
    __shared__ float t1[18][132];
    __shared__ float t2[18][132];
    int g = blockIdx.x, c = blockIdx.y, b = blockIdx.z;
    int tid = threadIdx.x;
    const unsigned short* i1 = in1 + (size_t)(b * 256 + c) * HWSZ;
    const unsigned short* i2 = in2 + (size_t)(b * 256 + c) * HWSZ;
    dw_load_tile(i1, g * 16, t1, tid);
    dw_load_tile(i2, g * 16, t2, tid);
    bool vc = (c < validc);
    float wr1[9], wr2[9];
#pragma unroll
    for (int j = 0; j < 9; ++j) {
        wr1[j] = vc ? w1[c * 9 + j] : 0.f;
        wr2[j] = vc ? w2[c * 9 + j] : 0.f;
    }
    __syncthreads();
    int rl = tid >> 4, px0 = (tid & 15) * 8;
    float a[8], bg[8];
    dw_compute8(t1, wr1, rl, px0, a);
    dw_compute8(t2, wr2, rl, px0, bg);
    float o[8];
#pragma unroll
    for (int j = 0; j < 8; ++j)
        o[j] = 0.5f * a[j] * (1.f + erff(a[j] * 0.70710678118654752f)) * bg[j];
    unsigned short* op = out + (size_t)(b * 256 + c) * HWSZ + (g * 16 + rl) * WID + px0;
    uint4 u;
    u.x = pk2(o[0], o[1]); u.y = pk2(o[2], o[3]); u.z = pk2(o[4], o[5]); u.w = pk2(o[6], o[7]);
    *(uint4*)op = u;
}

// ---------------- transpose [b][256][HW] bf16 -> [b][px][256] bf16 ----------------
__global__ __launch_bounds__(256) void k_trans(const unsigned short* __restrict__ gg,
    unsigned short* __restrict__ gT)
{
    __shared__ unsigned short lt[64][264];
    int px0 = blockIdx.x * 64, b = blockIdx.z;
    for (int idx = threadIdx.x; idx < 2048; idx += 256) {
        int ch = idx >> 3, chunk = idx & 7;
        uint4 u = *(const uint4*)(gg + ((size_t)(b * 256 + ch)) * HWSZ + px0 + chunk * 8);
        const unsigned short* pu = (const unsigned short*)&u;
#pragma unroll
        for (int i = 0; i < 8; ++i) lt[chunk * 8 + i][ch] = pu[i];
    }
    __syncthreads();
    for (int idx = threadIdx.x; idx < 2048; idx += 256) {
        int px = idx >> 5, cc = idx & 31;
        *(uint4*)(gT + ((size_t)b * HWSZ + px0 + px) * 256 + cc * 8) = *(const uint4*)&lt[px][cc * 8];
    }
}

// ---------------- DWT row pass ----------------
__global__ __launch_bounds__(256) void k_dwt_row(const float* __restrict__ xn, float* __restrict__ rowbuf)
{
    int bc = blockIdx.x;
    const float* ip = xn + (size_t)bc * HWSZ;
    float* lo = rowbuf + (size_t)bc * 8448;
    float* hi = rowbuf + (size_t)(768 + bc) * 8448;
    for (int idx = threadIdx.x; idx < 128 * 66; idx += 256) {
        int row = idx / 66, ow = idx - row * 66;
        const float* rp = ip + row * 128;
        int base = 2 * ow - 4;
        float v[6];
#pragma unroll
        for (int j = 0; j < 6; ++j) {
            int iw = base + j;
            v[j] = (iw >= 0 && iw < 128) ? rp[iw] : 0.f;
        }
        float lv = 0.f, hv = 0.f;
#pragma unroll
        for (int j = 0; j < 6; ++j) {
            lv += v[j] * c_lo[5 - j];
            hv += v[j] * c_hi[5 - j];
        }
        lo[idx] = lv; hi[idx] = hv;
    }
}

// ---------------- DWT col pass + band 3x3 dwconv ----------------
__global__ __launch_bounds__(256) void k_dwt_colconv(const float* __restrict__ rowbuf,
    const float* __restrict__ w5, const float* __restrict__ w7, const float* __restrict__ w9,
    float* __restrict__ bfilt)
{
    __shared__ float rb[136][66];
    __shared__ float bnd[66][66];
    int h = blockIdx.x, c = blockIdx.y, b = blockIdx.z;
    int bc = b * CCH + c;
    const float* src = rowbuf + (size_t)(h * 768 + bc) * 8448;
    for (int i = threadIdx.x; i < 136 * 66; i += 256) {
        int r = i / 66, cc = i - r * 66;
        rb[r][cc] = (r >= 4 && r < 132) ? src[(r - 4) * 66 + cc] : 0.f;
    }
    for (int fs = 0; fs < 2; ++fs) {
        __syncthreads();
        int band = fs * 2 + h;
        const float* fa = fs ? c_hi : c_lo;
        for (int i = threadIdx.x; i < 4356; i += 256) {
            int oh = i / 66, ow = i - oh * 66;
            float a = 0.f;
#pragma unroll
            for (int ki = 0; ki < 6; ++ki)
                a += fa[5 - ki] * rb[oh * 2 + ki][ow];
            bnd[oh][ow] = a;
        }
        __syncthreads();
        const float* wsel = (band < 2) ? w5 : (band == 2 ? w7 : w9);
        float wr[9];
#pragma unroll
        for (int j = 0; j < 9; ++j) wr[j] = wsel[c * 9 + j];
        float* op = bfilt + ((size_t)bc * 4 + band) * 4356;
        for (int i = threadIdx.x; i < 4356; i += 256) {
            int y = i / 66, xx = i - y * 66;
            float a = 0.f;
#pragma unroll
            for (int dy = 0; dy < 3; ++dy) {
                int yy = y + dy - 1;
                if (yy < 0 || yy >= 66) continue;
#pragma unroll
                for (int dx = 0; dx < 3; ++dx) {
                    int x2 = xx + dx - 1;
                    if (x2 < 0 || x2 >= 66) continue;
                    a += bnd[yy][x2] * wr[dy * 3 + dx];
                }
            }
            op[i] = a;
        }
    }
}

// ---------------- fused IDWT over 4 bands: 16 rows/block, 8px/thread, + q^2 reduce ----------------
__global__ __launch_bounds__(256) void k_idwt2(const float* __restrict__ bfilt,
    unsigned short* __restrict__ q, float* __restrict__ rq2)
{
    __shared__ float L[4][10][68];
    __shared__ float w4[4];
    int g = blockIdx.x;          // 0..7 -> rows 16g..16g+15
    int c = blockIdx.y, b = blockIdx.z;
    int tid = threadIdx.x;
    int bc = b * CCH + c;
    const float* bp = bfilt + (size_t)bc * 4 * 4356;
    for (int i = tid; i < 4 * 10 * 66; i += 256) {
        int band = i / 660, rem = i - band * 660;
        int rr = rem / 66, cc = rem - rr * 66;
        L[band][rr][cc] = bp[band * 4356 + (8 * g + rr) * 66 + cc];
    }
    __syncthreads();
    int rl = tid >> 4, px0 = (tid & 15) * 8;
    int oh = 16 * g + rl;
    int Tl = rl >> 1, pr = rl & 1;
    int mb = px0 >> 1;
    float acc[8];
#pragma unroll
    for (int j = 0; j < 8; ++j) acc[j] = 0.f;
#pragma unroll
    for (int band = 0; band < 4; ++band) {
        const float* fv = (band < 2) ? c_lo : c_hi;
        const float* fh = (band & 1) ? c_hi : c_lo;
        float fv3[3] = {fv[1 - pr], fv[3 - pr], fv[5 - pr]};
        float fhe[3] = {fh[1], fh[3], fh[5]};
        float fho[3] = {fh[0], fh[2], fh[4]};
#pragma unroll
        for (int i = 0; i < 3; ++i) {
            float r6[6];
#pragma unroll
            for (int m = 0; m < 6; ++m) r6[m] = L[band][Tl + i][mb + m];
#pragma unroll
            for (int jj = 0; jj < 4; ++jj) {
                float se = fhe[0] * r6[jj] + fhe[1] * r6[jj + 1] + fhe[2] * r6[jj + 2];
                float so = fho[0] * r6[jj] + fho[1] * r6[jj + 1] + fho[2] * r6[jj + 2];
                acc[2 * jj]     += fv3[i] * se;
                acc[2 * jj + 1] += fv3[i] * so;
            }
        }
    }
    unsigned short* op = q + (size_t)bc * HWSZ + oh * WID + px0;
    uint4 u;
    u.x = pk2(acc[0], acc[1]); u.y = pk2(acc[2], acc[3]);
    u.z = pk2(acc[4], acc[5]); u.w = pk2(acc[6], acc[7]);
    *(uint4*)op = u;
    float s = 0.f;
#pragma unroll
    for (int j = 0; j < 8; ++j) s += acc[j] * acc[j];
    for (int off = 32; off; off >>= 1) s += __shfl_down(s, off, 64);
    if ((tid & 63) == 0) w4[tid >> 6] = s;
    __syncthreads();
    if (tid == 0) atomicAdd(rq2 + bc, w4[0] + w4[1] + w4[2] + w4[3]);
}

// ---------------- finalize norms ----------------
__global__ __launch_bounds__(256) void k_fnorm(const float* __restrict__ rq2,
    const float* __restrict__ rk2, float* __restrict__ rq, float* __restrict__ rk)
{
    int i = blockIdx.x * 256 + threadIdx.x;
    if (i < 768) rq[i] = 1.f / fmaxf(sqrtf(rq2[i]), 1e-12f);
    else if (i < 1536) rk[i - 768] = 1.f / fmaxf(sqrtf(rk2[i - 768]), 1e-12f);
}

// ---------------- partial QK^T over an n-slice of 1024 (bf16 inputs) ----------------
__global__ __launch_bounds__(256) void k_qk_partial(const unsigned short* __restrict__ q,
    const unsigned short* __restrict__ kv, float* __restrict__ pS)
{
    int slice = blockIdx.x;
    int bh = blockIdx.y;
    int b = bh >> 2, h = bh & 3;
    __shared__ float qch[48][65];
    __shared__ float kch[48][65];
    float acc[3][3] = {{0.f}};
    int tid = threadIdx.x, dt = tid >> 4, et = tid & 15;
    const unsigned short* qbase = q + (size_t)(b * CCH + h * 48) * HWSZ;
    const unsigned short* kbase = kv + (size_t)(b * 384 + h * 48) * HWSZ;
    int n0s = slice * 1024;
    for (int n0 = n0s; n0 < n0s + 1024; n0 += 64) {
        for (int l = tid; l < 3072; l += 256) {
            int r = l >> 6, cc = l & 63;
            qch[r][cc] = b2f(qbase[(size_t)r * HWSZ + n0 + cc]);
            kch[r][cc] = b2f(kbase[(size_t)r * HWSZ + n0 + cc]);
        }
        __syncthreads();
#pragma unroll
        for (int nn = 0; nn < 64; ++nn) {
            float q0 = qch[dt][nn], q1 = qch[dt + 16][nn], q2 = qch[dt + 32][nn];
            float k0 = kch[et][nn], k1 = kch[et + 16][nn], k2 = kch[et + 32][nn];
            acc[0][0] += q0 * k0; acc[0][1] += q0 * k1; acc[0][2] += q0 * k2;
            acc[1][0] += q1 * k0; acc[1][1] += q1 * k1; acc[1][2] += q1 * k2;
            acc[2][0] += q2 * k0; acc[2][1] += q2 * k1; acc[2][2] += q2 * k2;
        }
        __syncthreads();
    }
    float* ps = pS + (size_t)(slice * 16 + bh) * 2304;
#pragma unroll
    for (int i = 0; i < 3; ++i)
#pragma unroll
        for (int j = 0; j < 3; ++j)
            ps[(dt + 16 * i) * 48 + (et + 16 * j)] = acc[i][j];
}

// ---------------- reduce partials, scale, softmax ----------------
__global__ __launch_bounds__(256) void k_attn_soft(const float* __restrict__ pS,
    const float* __restrict__ rq, const float* __restrict__ rk,
    const float* __restrict__ temp, float* __restrict__ attnw)
{
    int bh = blockIdx.x; int b = bh >> 2, h = bh & 3;
    __shared__ float S[48][49];
    int tid = threadIdx.x, dt = tid >> 4, et = tid & 15;
    float tv = temp[h];
#pragma unroll
    for (int i = 0; i < 3; ++i) {
#pragma unroll
        for (int j = 0; j < 3; ++j) {
            int d = dt + 16 * i, e = et + 16 * j;
            float s = 0.f;
            for (int sl = 0; sl < 16; ++sl)
                s += pS[(size_t)(sl * 16 + bh) * 2304 + d * 48 + e];
            S[d][e] = s * tv * rq[b * CCH + h * 48 + d] * rk[b * CCH + h * 48 + e];
        }
    }
    __syncthreads();
    if (tid < 48) {
        float mx = -1e30f;
        for (int e = 0; e < 48; ++e) mx = fmaxf(mx, S[tid][e]);
        float sum = 0.f;
        for (int e = 0; e < 48; ++e) sum += expf(S[tid][e] - mx);
        float inv = 1.f / sum;
        for (int e = 0; e < 48; ++e)
            attnw[((size_t)bh * 48 + tid) * 48 + e] = expf(S[tid][e] - mx) * inv;
    }
}

// ---------------- out = attn @ v -> transposed bf16 [b][px][192] ----------------
__global__ __launch_bounds__(256) void k_attn_v(const float* __restrict__ attnw,
    const unsigned short* __restrict__ kv, unsigned short* __restrict__ attoT)
{
    int px = blockIdx.x * 256 + threadIdx.x;
    int dg = blockIdx.y;
    int bh = blockIdx.z; int b = bh >> 2, h = bh & 3;
    __shared__ float aw[8][48];
    for (int l = threadIdx.x; l < 8 * 48; l += 256) {
        int i = l / 48, e = l - 48 * i;
        aw[i][e] = attnw[((size_t)bh * 48 + dg * 8 + i) * 48 + e];
    }
    __syncthreads();
    const unsigned short* vbase = kv + (size_t)(b * 384 + 192 + h * 48) * HWSZ + px;
    float acc[8] = {0.f};
#pragma unroll
    for (int e = 0; e < 48; ++e) {
        float vv = b2f(vbase[(size_t)e * HWSZ]);
#pragma unroll
        for (int i = 0; i < 8; ++i) acc[i] += aw[i][e] * vv;
    }
    unsigned short* ob = attoT + ((size_t)b * HWSZ + px) * CCH + h * 48 + dg * 8;
    uint4 u;
    u.x = pk2(acc[0], acc[1]); u.y = pk2(acc[2], acc[3]);
    u.z = pk2(acc[4], acc[5]); u.w = pk2(acc[6], acc[7]);
    *(uint4*)ob = u;
}

// ---------------- launcher ----------------
extern "C" void kernel_launch(void* const* d_in, const int* in_sizes, int n_in,
                              void* d_out, int out_size, void* d_ws, size_t ws_size,
                              hipStream_t stream)
{
    const float* x     = (const float*)d_in[0];
    const float* ln1g  = (const float*)d_in[1];
    const float* ln1b  = (const float*)d_in[2];
    const float* ln2g  = (const float*)d_in[3];
    const float* ln2b  = (const float*)d_in[4];
    const float* temp  = (const float*)d_in[5];
    const float* wqkv  = (const float*)d_in[6];
    const float* wqkvd = (const float*)d_in[7];
    const float* w5    = (const float*)d_in[8];
    const float* w7    = (const float*)d_in[9];
    const float* w9    = (const float*)d_in[10];
    const float* wattn = (const float*)d_in[11];
    const float* wffni = (const float*)d_in[12];
    const float* wffnd = (const float*)d_in[13];
    const float* wffno = (const float*)d_in[14];
    float* out = (float*)d_out;

    char* ws = (char*)d_ws;
    unsigned short* xnT = (unsigned short*)(ws + 0);              // 25.2MB (later xn2T)
    float* xn   = (float*)(ws + 25165824);                        // 50.3MB fp32 (later kvtmp/attoT/y1r)
    unsigned short* q = (unsigned short*)(ws + 75497472);         // 25.2MB bf16 (later y2r)
    unsigned short* kvb = (unsigned short*)(ws + 100663296);      // 50.3MB bf16 kv
    float* bfilt = (float*)(ws + 100663296);                      // 53.5MB (dead before kvb written)
    float* rowbuf = (float*)(ws + 154189824);                     // 51.9MB -> ends 206094336
    const size_t SM = 226492416;
    float* rq2   = (float*)(ws + SM);
    float* rk2   = (float*)(ws + SM + 4096);
    float* rq    = (float*)(ws + SM + 8192);
    float* rk    = (float*)(ws + SM + 12288);
    float* pS    = (float*)(ws + SM + 16384);                     // 2359296, aliased by attnw
    float* attnw = pS;
    unsigned short* wq_b  = (unsigned short*)(ws + SM + 2375680); // 147456
    unsigned short* wat_b = (unsigned short*)(ws + SM + 2523136); // 73728
    unsigned short* wfi_b = (unsigned short*)(ws + SM + 2596864); // 393216
    unsigned short* wfo_b = (unsigned short*)(ws + SM + 2990080); // 196608
    const size_t NEED = SM + 3186688;
    if (ws_size < NEED) return;

    unsigned short* kvtmp = (unsigned short*)xn;
    unsigned short* attoT = (unsigned short*)xn;
    unsigned short* y1r = (unsigned short*)(ws + 25165824);       // 33.5MB
    unsigned short* y2r = (unsigned short*)(ws + 75497472);       // 33.5MB (kv dead by then)
    unsigned short* gg  = (unsigned short*)(ws + 125829120);      // 33.5MB
    unsigned short* gT  = (unsigned short*)(ws + 192937984);      // 33.5MB -> ends at SM

    dim3 blk(256);

    // 0. weights -> bf16 (padded); zero norm accumulators
    hipMemsetAsync(ws + SM, 0, 8192, stream);
    k_wconv<<<288, blk, 0, stream>>>(wqkv, wq_b, 384, 192, 192, 73728);
    k_wconv<<<144, blk, 0, stream>>>(wattn, wat_b, 192, 192, 192, 36864);
    k_wconv<<<384, blk, 0, stream>>>(wffni, wfi_b, 510, 192, 192, 98304);
    k_wconv<<<384, blk, 0, stream>>>(wffni + 510 * 192, wfi_b + 512 * 192, 510, 192, 192, 98304);
    k_wconv<<<384, blk, 0, stream>>>(wffno, wfo_b, 192, 510, 512, 98304);

    // 1. LN1 -> xn fp32 + xnT bf16
    k_ln<1><<<256, blk, 0, stream>>>(x, ln1g, ln1b, xn, xnT);

    // 2. SSL: row dwt -> col dwt + band conv -> fused idwt (q bf16 + q^2 sums)
    k_dwt_row<<<768, blk, 0, stream>>>(xn, rowbuf);
    k_dwt_colconv<<<dim3(2, CCH, BB), blk, 0, stream>>>(rowbuf, w5, w7, w9, bfilt);
    k_idwt2<<<dim3(8, CCH, BB), blk, 0, stream>>>(bfilt, q, rq2);

    // 3. kv = dw3x3(conv1x1(xn, w_qkv)) bf16, k^2 sums fused on half 0
    for (int h = 0; h < 2; ++h) {
        k_gemm<1, 0><<<dim3(64, 3, BB), blk, 0, stream>>>(xnT, wq_b + (size_t)h * 192 * 192,
                                                          kvtmp, nullptr, 192, 192, 192, 192);
        if (h == 0)
            k_dw8<1><<<dim3(8, 192, BB), blk, 0, stream>>>(kvtmp, wqkvd, kvb, rk2, 192, 0, 384, 0);
        else
            k_dw8<0><<<dim3(8, 192, BB), blk, 0, stream>>>(kvtmp, wqkvd + 192 * 9, kvb, nullptr, 192, 0, 384, 192);
    }

    // 4. norms + attention
    k_fnorm<<<6, blk, 0, stream>>>(rq2, rk2, rq, rk);
    k_qk_partial<<<dim3(16, 16), blk, 0, stream>>>(q, kvb, pS);
    k_attn_soft<<<16, blk, 0, stream>>>(pS, rq, rk, temp, attnw);
    k_attn_v<<<dim3(64, 6, 16), blk, 0, stream>>>(attnw, kvb, attoT);

    // 5. d_out = x + conv1x1(atto, w_attn_out)
    k_gemm<0, 1><<<dim3(64, 3, BB), blk, 0, stream>>>(attoT, wat_b, out, x, 192, 192, 192, 192);

    // 6. xn2T = LN2(d_out)
    k_ln<0><<<256, blk, 0, stream>>>(out, ln2g, ln2b, nullptr, xnT);

    // 7. GDFN in 2 hid-chunks of 256
    for (int ck = 0; ck < 2; ++ck) {
        int validc = (ck == 0) ? 256 : 254;
        k_gemm<1, 0><<<dim3(64, 4, BB), blk, 0, stream>>>(xnT, wfi_b + (size_t)(ck * 256) * 192,
                                                          y1r, nullptr, 192, 192, 192, 256);
        k_gemm<1, 0><<<dim3(64, 4, BB), blk, 0, stream>>>(xnT, wfi_b + (size_t)(512 + ck * 256) * 192,
                                                          y2r, nullptr, 192, 192, 192, 256);
        k_dw8gate<<<dim3(8, 256, BB), blk, 0, stream>>>(y1r, y2r, wffnd + (size_t)(ck * 256) * 9,
                                                        wffnd + (size_t)(510 + ck * 256) * 9, gg, validc);
        k_trans<<<dim3(256, 1, BB), blk, 0, stream>>>(gg, gT);
        k_gemm<0, 1><<<dim3(64, 3, BB), blk, 0, stream>>>(gT, wfo_b + ck * 256, out, out, 256, 256, 512, 192);
    }
}

// Round 5
// 700.948 us; speedup vs baseline: 9.0489x; 1.1795x over previous
//
#include <hip/hip_runtime.h>
#include <math.h>

#define HWSZ 16384
#define WID 128
#define HEI 128
#define CCH 192
#define BB 4

typedef short v8s __attribute__((ext_vector_type(8)));
typedef float f32x4 __attribute__((ext_vector_type(4)));

__device__ __constant__ float c_lo[6] = {0.035226291882100656f, -0.08544127388224149f, -0.13501102001039084f,
                                         0.4598775021193313f, 0.8068915093133388f, 0.3326705529509569f};
__device__ __constant__ float c_hi[6] = {-0.3326705529509569f, 0.8068915093133388f, -0.4598775021193313f,
                                         -0.13501102001039084f, 0.08544127388224149f, 0.035226291882100656f};

__device__ __forceinline__ float b2f(unsigned short h) { return __uint_as_float(((unsigned int)h) << 16); }
__device__ __forceinline__ unsigned short f2b(float f) {
    unsigned int u = __float_as_uint(f);
    return (unsigned short)((u + 0x7fffu + ((u >> 16) & 1u)) >> 16);
}
__device__ __forceinline__ unsigned int pk2(float a, float b) {
    return (unsigned int)f2b(a) | ((unsigned int)f2b(b) << 16);
}

// ---------------- weight fp32 -> bf16 with row/col zero-pad ----------------
__global__ __launch_bounds__(256) void k_wconv(const float* __restrict__ src,
    unsigned short* __restrict__ dst, int rows, int cols, int dcols, int total)
{
    int i = blockIdx.x * 256 + threadIdx.x;
    if (i >= total) return;
    int r = i / dcols, c = i - r * dcols;
    float v = (c < cols && r < rows) ? src[r * cols + c] : 0.f;
    dst[i] = f2b(v);
}

// ---------------- LayerNorm over channel dim; writes transposed bf16 (+opt fp32 spatial) ----------------
template<int WRITE_F32>
__global__ __launch_bounds__(256) void k_ln(const float* __restrict__ x,
    const float* __restrict__ g, const float* __restrict__ bta,
    float* __restrict__ xsp, unsigned short* __restrict__ xT)
{
    int pg = blockIdx.x * 256 + threadIdx.x;
    int b = pg >> 14, p = pg & 16383;
    const float* xp = x + (size_t)b * CCH * HWSZ + p;
    float s = 0.f, s2 = 0.f;
    for (int c = 0; c < CCH; ++c) {
        float v = xp[(size_t)c * HWSZ];
        s += v; s2 += v * v;
    }
    float mu = s * (1.f / CCH);
    float var = s2 * (1.f / CCH) - mu * mu;
    float rs = rsqrtf(var + 1e-5f);
    unsigned short* tr = xT + ((size_t)b * HWSZ + p) * CCH;
    float* sp = xsp + (size_t)b * CCH * HWSZ + p;
    for (int c0 = 0; c0 < CCH; c0 += 8) {
        float vv[8];
#pragma unroll
        for (int i = 0; i < 8; ++i) {
            float v = xp[(size_t)(c0 + i) * HWSZ];
            v = (v - mu) * rs * g[c0 + i] + bta[c0 + i];
            vv[i] = v;
            if (WRITE_F32) sp[(size_t)(c0 + i) * HWSZ] = v;
        }
        uint4 u;
        u.x = pk2(vv[0], vv[1]); u.y = pk2(vv[2], vv[3]);
        u.z = pk2(vv[4], vv[5]); u.w = pk2(vv[6], vv[7]);
        *(uint4*)(tr + c0) = u;
    }
}

// ---------------- bf16 MFMA GEMM (optional per-batch weight stride) ----------------
template<int OUT_BF16, int ADD>
__global__ __launch_bounds__(256) void k_gemm(
    const unsigned short* __restrict__ X, const unsigned short* __restrict__ W,
    void* __restrict__ outp, const float* __restrict__ addsrc,
    int K, int ldx, int ldw, int Mtot, int wstrideB)
{
    int lane = threadIdx.x & 63, wv = threadIdx.x >> 6;
    int b = blockIdx.z;
    int r = lane & 15, koct = lane >> 4;
    int pxb = blockIdx.x * 256 + wv * 64;
    int co0 = blockIdx.y * 64;
    const unsigned short* xb = X + ((size_t)b * HWSZ + pxb + r) * ldx + koct * 8;
    const unsigned short* wb = W + (size_t)b * wstrideB + (size_t)(co0 + r) * ldw + koct * 8;
    f32x4 z = {0.f, 0.f, 0.f, 0.f};
    f32x4 acc[4][4];
#pragma unroll
    for (int i = 0; i < 4; ++i)
#pragma unroll
        for (int j = 0; j < 4; ++j) acc[i][j] = z;

    for (int k0 = 0; k0 < K; k0 += 32) {
        v8s a0 = *(const v8s*)(wb + k0);
        v8s a1 = *(const v8s*)(wb + 16 * ldw + k0);
        v8s a2 = *(const v8s*)(wb + 32 * ldw + k0);
        v8s a3 = *(const v8s*)(wb + 48 * ldw + k0);
        v8s b0 = *(const v8s*)(xb + k0);
        v8s b1 = *(const v8s*)(xb + 16 * ldx + k0);
        v8s b2 = *(const v8s*)(xb + 32 * ldx + k0);
        v8s b3 = *(const v8s*)(xb + 48 * ldx + k0);
        acc[0][0] = __builtin_amdgcn_mfma_f32_16x16x32_bf16(a0, b0, acc[0][0], 0, 0, 0);
        acc[0][1] = __builtin_amdgcn_mfma_f32_16x16x32_bf16(a0, b1, acc[0][1], 0, 0, 0);
        acc[0][2] = __builtin_amdgcn_mfma_f32_16x16x32_bf16(a0, b2, acc[0][2], 0, 0, 0);
        acc[0][3] = __builtin_amdgcn_mfma_f32_16x16x32_bf16(a0, b3, acc[0][3], 0, 0, 0);
        acc[1][0] = __builtin_amdgcn_mfma_f32_16x16x32_bf16(a1, b0, acc[1][0], 0, 0, 0);
        acc[1][1] = __builtin_amdgcn_mfma_f32_16x16x32_bf16(a1, b1, acc[1][1], 0, 0, 0);
        acc[1][2] = __builtin_amdgcn_mfma_f32_16x16x32_bf16(a1, b2, acc[1][2], 0, 0, 0);
        acc[1][3] = __builtin_amdgcn_mfma_f32_16x16x32_bf16(a1, b3, acc[1][3], 0, 0, 0);
        acc[2][0] = __builtin_amdgcn_mfma_f32_16x16x32_bf16(a2, b0, acc[2][0], 0, 0, 0);
        acc[2][1] = __builtin_amdgcn_mfma_f32_16x16x32_bf16(a2, b1, acc[2][1], 0, 0, 0);
        acc[2][2] = __builtin_amdgcn_mfma_f32_16x16x32_bf16(a2, b2, acc[2][2], 0, 0, 0);
        acc[2][3] = __builtin_amdgcn_mfma_f32_16x16x32_bf16(a2, b3, acc[2][3], 0, 0, 0);
        acc[3][0] = __builtin_amdgcn_mfma_f32_16x16x32_bf16(a3, b0, acc[3][0], 0, 0, 0);
        acc[3][1] = __builtin_amdgcn_mfma_f32_16x16x32_bf16(a3, b1, acc[3][1], 0, 0, 0);
        acc[3][2] = __builtin_amdgcn_mfma_f32_16x16x32_bf16(a3, b2, acc[3][2], 0, 0, 0);
        acc[3][3] = __builtin_amdgcn_mfma_f32_16x16x32_bf16(a3, b3, acc[3][3], 0, 0, 0);
    }

    int row4 = koct * 4;
#pragma unroll
    for (int c = 0; c < 4; ++c) {
        int corow = co0 + c * 16 + row4;
#pragma unroll
        for (int nf = 0; nf < 4; ++nf) {
            int pxo = pxb + nf * 16 + r;
#pragma unroll
            for (int j = 0; j < 4; ++j) {
                size_t oi = ((size_t)b * Mtot + corow + j) * HWSZ + pxo;
                float v = acc[c][nf][j];
                if (ADD) v += addsrc[oi];
                if (OUT_BF16) ((unsigned short*)outp)[oi] = f2b(v);
                else ((float*)outp)[oi] = v;
            }
        }
    }
}

// ---------------- depthwise helpers ----------------
__device__ __forceinline__ void dw_load_tile(const unsigned short* __restrict__ ip,
    int r0, float (&tile)[18][132], int tid)
{
    for (int e = tid; e < 576; e += 256) {
        int r = e >> 5, q4 = e & 31;
        int gr = r0 - 1 + r;
        float v0 = 0.f, v1 = 0.f, v2 = 0.f, v3 = 0.f;
        if (gr >= 0 && gr < HEI) {
            uint2 u = *(const uint2*)(ip + gr * WID + q4 * 4);
            const unsigned short* pu = (const unsigned short*)&u;
            v0 = b2f(pu[0]); v1 = b2f(pu[1]); v2 = b2f(pu[2]); v3 = b2f(pu[3]);
        }
        int cb = 1 + q4 * 4;
        tile[r][cb] = v0; tile[r][cb + 1] = v1; tile[r][cb + 2] = v2; tile[r][cb + 3] = v3;
    }
    if (tid < 18) { tile[tid][0] = 0.f; tile[tid][129] = 0.f; }
}

__device__ __forceinline__ void dw_compute8(const float (&tile)[18][132],
    const float* wr, int rl, int px0, float (&o)[8])
{
    float r0[10], r1[10], r2[10];
#pragma unroll
    for (int i = 0; i < 10; ++i) {
        r0[i] = tile[rl][px0 + i];
        r1[i] = tile[rl + 1][px0 + i];
        r2[i] = tile[rl + 2][px0 + i];
    }
#pragma unroll
    for (int j = 0; j < 8; ++j) {
        o[j] = r0[j] * wr[0] + r0[j + 1] * wr[1] + r0[j + 2] * wr[2]
             + r1[j] * wr[3] + r1[j + 1] * wr[4] + r1[j + 2] * wr[5]
             + r2[j] * wr[6] + r2[j + 1] * wr[7] + r2[j + 2] * wr[8];
    }
}

// ---------------- depthwise 3x3 bf16, 16 rows/block, 8px/thread; opt k^2 reduce ----------------
template<int REDUCE>
__global__ __launch_bounds__(256) void k_dw8(const unsigned short* __restrict__ in,
    const float* __restrict__ w, unsigned short* __restrict__ out, float* __restrict__ red,
    int inCtot, int inCoff, int outCtot, int outCoff)
{
    __shared__ float tile[18][132];
    int g = blockIdx.x, c = blockIdx.y, b = blockIdx.z;
    int tid = threadIdx.x;
    const unsigned short* ip = in + (size_t)(b * inCtot + inCoff + c) * HWSZ;
    dw_load_tile(ip, g * 16, tile, tid);
    float wr[9];
#pragma unroll
    for (int j = 0; j < 9; ++j) wr[j] = w[c * 9 + j];
    __syncthreads();
    int rl = tid >> 4, px0 = (tid & 15) * 8;
    float o[8];
    dw_compute8(tile, wr, rl, px0, o);
    unsigned short* op = out + (size_t)(b * outCtot + outCoff + c) * HWSZ + (g * 16 + rl) * WID + px0;
    uint4 u;
    u.x = pk2(o[0], o[1]); u.y = pk2(o[2], o[3]); u.z = pk2(o[4], o[5]); u.w = pk2(o[6], o[7]);
    *(uint4*)op = u;
    if (REDUCE) {
        float s = 0.f;
#pragma unroll
        for (int j = 0; j < 8; ++j) s += o[j] * o[j];
        for (int off = 32; off; off >>= 1) s += __shfl_down(s, off, 64);
        __shared__ float w4[4];
        if ((tid & 63) == 0) w4[tid >> 6] = s;
        __syncthreads();
        if (tid == 0) atomicAdd(red + b * CCH + c, w4[0] + w4[1] + w4[2] + w4[3]);
    }
}

// ---------------- fused FFN: dw3x3(y1), dw3x3(y2), gelu(a)*b -> bf16 channel-major ----------------
__global__ __launch_bounds__(256) void k_dw8gate(const unsigned short* __restrict__ in1,
    const unsigned short* __restrict__ in2, const float* __restrict__ w1,
    const float* __restrict__ w2, unsigned short* __restrict__ out, int validc)
{
    __shared__ float t1[18][132];
    __shared__ float t2[18][132];
    int g = blockIdx.x, c = blockIdx.y, b = blockIdx.z;
    int tid = threadIdx.x;
    const unsigned short* i1 = in1 + (size_t)(b * 256 + c) * HWSZ;
    const unsigned short* i2 = in2 + (size_t)(b * 256 + c) * HWSZ;
    dw_load_tile(i1, g * 16, t1, tid);
    dw_load_tile(i2, g * 16, t2, tid);
    bool vc = (c < validc);
    float wr1[9], wr2[9];
#pragma unroll
    for (int j = 0; j < 9; ++j) {
        wr1[j] = vc ? w1[c * 9 + j] : 0.f;
        wr2[j] = vc ? w2[c * 9 + j] : 0.f;
    }
    __syncthreads();
    int rl = tid >> 4, px0 = (tid & 15) * 8;
    float a[8], bg[8];
    dw_compute8(t1, wr1, rl, px0, a);
    dw_compute8(t2, wr2, rl, px0, bg);
    float o[8];
#pragma unroll
    for (int j = 0; j < 8; ++j)
        o[j] = 0.5f * a[j] * (1.f + erff(a[j] * 0.70710678118654752f)) * bg[j];
    unsigned short* op = out + (size_t)(b * 256 + c) * HWSZ + (g * 16 + rl) * WID + px0;
    uint4 u;
    u.x = pk2(o[0], o[1]); u.y = pk2(o[2], o[3]); u.z = pk2(o[4], o[5]); u.w = pk2(o[6], o[7]);
    *(uint4*)op = u;
}

// ---------------- transpose [b][CT][HW] bf16 -> [b][px][CT] bf16 ----------------
template<int CT>
__global__ __launch_bounds__(256) void k_transT(const unsigned short* __restrict__ gg,
    unsigned short* __restrict__ gT, int inCtot, int inCoff)
{
    __shared__ unsigned short lt[64][CT + 8];
    int px0 = blockIdx.x * 64, b = blockIdx.z;
    for (int idx = threadIdx.x; idx < 8 * CT; idx += 256) {
        int ch = idx >> 3, chunk = idx & 7;
        uint4 u = *(const uint4*)(gg + ((size_t)(b * inCtot + inCoff + ch)) * HWSZ + px0 + chunk * 8);
        const unsigned short* pu = (const unsigned short*)&u;
#pragma unroll
        for (int i = 0; i < 8; ++i) lt[chunk * 8 + i][ch] = pu[i];
    }
    __syncthreads();
    for (int idx = threadIdx.x; idx < 8 * CT; idx += 256) {
        int px = idx / (CT / 8), cc = idx - px * (CT / 8);
        *(uint4*)(gT + ((size_t)b * HWSZ + px0 + px) * CT + cc * 8) = *(const uint4*)&lt[px][cc * 8];
    }
}

// ---------------- DWT row pass (bf16 out) ----------------
__global__ __launch_bounds__(256) void k_dwt_row(const float* __restrict__ xn, unsigned short* __restrict__ rowbuf)
{
    int bc = blockIdx.x;
    const float* ip = xn + (size_t)bc * HWSZ;
    unsigned short* lo = rowbuf + (size_t)bc * 8448;
    unsigned short* hi = rowbuf + (size_t)(768 + bc) * 8448;
    for (int idx = threadIdx.x; idx < 128 * 66; idx += 256) {
        int row = idx / 66, ow = idx - row * 66;
        const float* rp = ip + row * 128;
        int base = 2 * ow - 4;
        float v[6];
#pragma unroll
        for (int j = 0; j < 6; ++j) {
            int iw = base + j;
            v[j] = (iw >= 0 && iw < 128) ? rp[iw] : 0.f;
        }
        float lv = 0.f, hv = 0.f;
#pragma unroll
        for (int j = 0; j < 6; ++j) {
            lv += v[j] * c_lo[5 - j];
            hv += v[j] * c_hi[5 - j];
        }
        lo[idx] = f2b(lv); hi[idx] = f2b(hv);
    }
}

// ---------------- DWT col pass + band 3x3 dwconv (bf16 in/out) ----------------
__global__ __launch_bounds__(256) void k_dwt_colconv(const unsigned short* __restrict__ rowbuf,
    const float* __restrict__ w5, const float* __restrict__ w7, const float* __restrict__ w9,
    unsigned short* __restrict__ bfilt)
{
    __shared__ float rb[136][66];
    __shared__ float bnd[66][66];
    int h = blockIdx.x, c = blockIdx.y, b = blockIdx.z;
    int bc = b * CCH + c;
    const unsigned short* src = rowbuf + (size_t)(h * 768 + bc) * 8448;
    for (int i = threadIdx.x; i < 136 * 66; i += 256) {
        int r = i / 66, cc = i - r * 66;
        rb[r][cc] = (r >= 4 && r < 132) ? b2f(src[(r - 4) * 66 + cc]) : 0.f;
    }
    for (int fs = 0; fs < 2; ++fs) {
        __syncthreads();
        int band = fs * 2 + h;
        const float* fa = fs ? c_hi : c_lo;
        for (int i = threadIdx.x; i < 4356; i += 256) {
            int oh = i / 66, ow = i - oh * 66;
            float a = 0.f;
#pragma unroll
            for (int ki = 0; ki < 6; ++ki)
                a += fa[5 - ki] * rb[oh * 2 + ki][ow];
            bnd[oh][ow] = a;
        }
        __syncthreads();
        const float* wsel = (band < 2) ? w5 : (band == 2 ? w7 : w9);
        float wr[9];
#pragma unroll
        for (int j = 0; j < 9; ++j) wr[j] = wsel[c * 9 + j];
        unsigned short* op = bfilt + ((size_t)bc * 4 + band) * 4356;
        for (int i = threadIdx.x; i < 4356; i += 256) {
            int y = i / 66, xx = i - y * 66;
            float a = 0.f;
#pragma unroll
            for (int dy = 0; dy < 3; ++dy) {
                int yy = y + dy - 1;
                if (yy < 0 || yy >= 66) continue;
#pragma unroll
                for (int dx = 0; dx < 3; ++dx) {
                    int x2 = xx + dx - 1;
                    if (x2 < 0 || x2 >= 66) continue;
                    a += bnd[yy][x2] * wr[dy * 3 + dx];
                }
            }
            op[i] = f2b(a);
        }
    }
}

// ---------------- fused IDWT over 4 bands: 16 rows/block, 8px/thread, + q^2 reduce ----------------
__global__ __launch_bounds__(256) void k_idwt2(const unsigned short* __restrict__ bfilt,
    unsigned short* __restrict__ q, float* __restrict__ rq2)
{
    __shared__ float L[4][10][68];
    __shared__ float w4[4];
    int g = blockIdx.x;
    int c = blockIdx.y, b = blockIdx.z;
    int tid = threadIdx.x;
    int bc = b * CCH + c;
    const unsigned short* bp = bfilt + (size_t)bc * 4 * 4356;
    for (int i = tid; i < 4 * 10 * 66; i += 256) {
        int band = i / 660, rem = i - band * 660;
        int rr = rem / 66, cc = rem - rr * 66;
        L[band][rr][cc] = b2f(bp[band * 4356 + (8 * g + rr) * 66 + cc]);
    }
    __syncthreads();
    int rl = tid >> 4, px0 = (tid & 15) * 8;
    int oh = 16 * g + rl;
    int Tl = rl >> 1, pr = rl & 1;
    int mb = px0 >> 1;
    float acc[8];
#pragma unroll
    for (int j = 0; j < 8; ++j) acc[j] = 0.f;
#pragma unroll
    for (int band = 0; band < 4; ++band) {
        const float* fv = (band < 2) ? c_lo : c_hi;
        const float* fh = (band & 1) ? c_hi : c_lo;
        float fv3[3] = {fv[1 - pr], fv[3 - pr], fv[5 - pr]};
        float fhe[3] = {fh[1], fh[3], fh[5]};
        float fho[3] = {fh[0], fh[2], fh[4]};
#pragma unroll
        for (int i = 0; i < 3; ++i) {
            float r6[6];
#pragma unroll
            for (int m = 0; m < 6; ++m) r6[m] = L[band][Tl + i][mb + m];
#pragma unroll
            for (int jj = 0; jj < 4; ++jj) {
                float se = fhe[0] * r6[jj] + fhe[1] * r6[jj + 1] + fhe[2] * r6[jj + 2];
                float so = fho[0] * r6[jj] + fho[1] * r6[jj + 1] + fho[2] * r6[jj + 2];
                acc[2 * jj]     += fv3[i] * se;
                acc[2 * jj + 1] += fv3[i] * so;
            }
        }
    }
    unsigned short* op = q + (size_t)bc * HWSZ + oh * WID + px0;
    uint4 u;
    u.x = pk2(acc[0], acc[1]); u.y = pk2(acc[2], acc[3]);
    u.z = pk2(acc[4], acc[5]); u.w = pk2(acc[6], acc[7]);
    *(uint4*)op = u;
    float s = 0.f;
#pragma unroll
    for (int j = 0; j < 8; ++j) s += acc[j] * acc[j];
    for (int off = 32; off; off >>= 1) s += __shfl_down(s, off, 64);
    if ((tid & 63) == 0) w4[tid >> 6] = s;
    __syncthreads();
    if (tid == 0) atomicAdd(rq2 + bc, w4[0] + w4[1] + w4[2] + w4[3]);
}

// ---------------- finalize norms ----------------
__global__ __launch_bounds__(256) void k_fnorm(const float* __restrict__ rq2,
    const float* __restrict__ rk2, float* __restrict__ rq, float* __restrict__ rk)
{
    int i = blockIdx.x * 256 + threadIdx.x;
    if (i < 768) rq[i] = 1.f / fmaxf(sqrtf(rq2[i]), 1e-12f);
    else if (i < 1536) rk[i - 768] = 1.f / fmaxf(sqrtf(rk2[i - 768]), 1e-12f);
}

// ---------------- QK^T via MFMA: grid (16 n-slices, 16 bh), 4 waves ----------------
__global__ __launch_bounds__(256) void k_qk_mfma(const unsigned short* __restrict__ q,
    const unsigned short* __restrict__ kv, float* __restrict__ pS)
{
    __shared__ float red[4][2304];
    int slice = blockIdx.x, bh = blockIdx.y;
    int b = bh >> 2, h = bh & 3;
    int wv = threadIdx.x >> 6, lane = threadIdx.x & 63;
    int r = lane & 15, koct = lane >> 4;
    const unsigned short* qb = q + (size_t)(b * CCH + h * 48) * HWSZ;
    const unsigned short* kb = kv + (size_t)(b * 384 + h * 48) * HWSZ;
    int n0 = slice * 1024 + wv * 256 + koct * 8;
    f32x4 z = {0.f, 0.f, 0.f, 0.f};
    f32x4 acc[3][3];
#pragma unroll
    for (int i = 0; i < 3; ++i)
#pragma unroll
        for (int j = 0; j < 3; ++j) acc[i][j] = z;
    for (int step = 0; step < 8; ++step) {
        int n = n0 + step * 32;
        v8s qf[3], kf[3];
#pragma unroll
        for (int i = 0; i < 3; ++i) {
            qf[i] = *(const v8s*)(qb + (size_t)(16 * i + r) * HWSZ + n);
            kf[i] = *(const v8s*)(kb + (size_t)(16 * i + r) * HWSZ + n);
        }
#pragma unroll
        for (int i = 0; i < 3; ++i)
#pragma unroll
            for (int j = 0; j < 3; ++j)
                acc[i][j] = __builtin_amdgcn_mfma_f32_16x16x32_bf16(qf[i], kf[j], acc[i][j], 0, 0, 0);
    }
    // C layout: row(d) = koct*4 + jj, col(e) = r
#pragma unroll
    for (int i = 0; i < 3; ++i)
#pragma unroll
        for (int j = 0; j < 3; ++j)
#pragma unroll
            for (int jj = 0; jj < 4; ++jj)
                red[wv][(16 * i + koct * 4 + jj) * 48 + 16 * j + r] = acc[i][j][jj];
    __syncthreads();
    float* ps = pS + (size_t)(slice * 16 + bh) * 2304;
    for (int e = threadIdx.x; e < 2304; e += 256)
        ps[e] = red[0][e] + red[1][e] + red[2][e] + red[3][e];
}

// ---------------- reduce partials, scale, softmax ----------------
__global__ __launch_bounds__(256) void k_attn_soft(const float* __restrict__ pS,
    const float* __restrict__ rq, const float* __restrict__ rk,
    const float* __restrict__ temp, float* __restrict__ attnw)
{
    int bh = blockIdx.x; int b = bh >> 2, h = bh & 3;
    __shared__ float S[48][49];
    int tid = threadIdx.x, dt = tid >> 4, et = tid & 15;
    float tv = temp[h];
#pragma unroll
    for (int i = 0; i < 3; ++i) {
#pragma unroll
        for (int j = 0; j < 3; ++j) {
            int d = dt + 16 * i, e = et + 16 * j;
            float s = 0.f;
            for (int sl = 0; sl < 16; ++sl)
                s += pS[(size_t)(sl * 16 + bh) * 2304 + d * 48 + e];
            S[d][e] = s * tv * rq[b * CCH + h * 48 + d] * rk[b * CCH + h * 48 + e];
        }
    }
    __syncthreads();
    if (tid < 48) {
        float mx = -1e30f;
        for (int e = 0; e < 48; ++e) mx = fmaxf(mx, S[tid][e]);
        float sum = 0.f;
        for (int e = 0; e < 48; ++e) sum += expf(S[tid][e] - mx);
        float inv = 1.f / sum;
        for (int e = 0; e < 48; ++e)
            attnw[((size_t)bh * 48 + tid) * 48 + e] = expf(S[tid][e] - mx) * inv;
    }
}

// ---------------- fuse Wattn @ blockdiag(attn) -> per-batch bf16 weight [192][192] ----------------
__global__ __launch_bounds__(192) void k_wfuse(const float* __restrict__ wattn,
    const float* __restrict__ attnw, unsigned short* __restrict__ wf)
{
    int co = blockIdx.x, b = blockIdx.y;
    int ce = threadIdx.x;           // 0..191
    int h = ce / 48, e = ce - h * 48;
    const float* wrow = wattn + (size_t)co * 192 + h * 48;
    const float* arow = attnw + ((size_t)(b * 4 + h) * 48) * 48 + e;
    float acc = 0.f;
#pragma unroll 8
    for (int d = 0; d < 48; ++d)
        acc += wrow[d] * arow[(size_t)d * 48];
    wf[((size_t)b * 192 + co) * 192 + ce] = f2b(acc);
}

// ---------------- launcher ----------------
extern "C" void kernel_launch(void* const* d_in, const int* in_sizes, int n_in,
                              void* d_out, int out_size, void* d_ws, size_t ws_size,
                              hipStream_t stream)
{
    const float* x     = (const float*)d_in[0];
    const float* ln1g  = (const float*)d_in[1];
    const float* ln1b  = (const float*)d_in[2];
    const float* ln2g  = (const float*)d_in[3];
    const float* ln2b  = (const float*)d_in[4];
    const float* temp  = (const float*)d_in[5];
    const float* wqkv  = (const float*)d_in[6];
    const float* wqkvd = (const float*)d_in[7];
    const float* w5    = (const float*)d_in[8];
    const float* w7    = (const float*)d_in[9];
    const float* w9    = (const float*)d_in[10];
    const float* wattn = (const float*)d_in[11];
    const float* wffni = (const float*)d_in[12];
    const float* wffnd = (const float*)d_in[13];
    const float* wffno = (const float*)d_in[14];
    float* out = (float*)d_out;

    char* ws = (char*)d_ws;
    unsigned short* xnT = (unsigned short*)(ws + 0);              // 25.2MB (later xn2T)
    float* xn   = (float*)(ws + 25165824);                        // 50.3MB fp32 (later kvtmp/vT/y1r)
    unsigned short* q = (unsigned short*)(ws + 75497472);         // 25.2MB bf16 (later y2r)
    unsigned short* kvb = (unsigned short*)(ws + 100663296);      // 50.3MB bf16 kv
    unsigned short* bfilt = (unsigned short*)(ws + 100663296);    // 26.8MB bf16 (dead before kvb)
    unsigned short* rowbuf = (unsigned short*)(ws + 154189824);   // 26.0MB bf16
    const size_t SM = 226492416;
    float* rq2   = (float*)(ws + SM);
    float* rk2   = (float*)(ws + SM + 4096);
    float* rq    = (float*)(ws + SM + 8192);
    float* rk    = (float*)(ws + SM + 12288);
    float* pS    = (float*)(ws + SM + 16384);                     // 2359296, aliased by attnw
    float* attnw = pS;
    unsigned short* wq_b  = (unsigned short*)(ws + SM + 2375680); // 147456
    unsigned short* wat_b = (unsigned short*)(ws + SM + 2523136); // 73728 (unused now, kept for layout)
    unsigned short* wfi_b = (unsigned short*)(ws + SM + 2596864); // 393216
    unsigned short* wfo_b = (unsigned short*)(ws + SM + 2990080); // 196608
    unsigned short* wf_b  = (unsigned short*)(ws + SM + 3186688); // 294912 per-batch fused attn-out
    const size_t NEED = SM + 3481600;
    if (ws_size < NEED) return;
    (void)wat_b;

    unsigned short* kvtmp = (unsigned short*)xn;
    unsigned short* vT    = (unsigned short*)xn;                  // [b][px][192] bf16, 25.2MB
    unsigned short* y1r = (unsigned short*)(ws + 25165824);
    unsigned short* y2r = (unsigned short*)(ws + 75497472);
    unsigned short* gg  = (unsigned short*)(ws + 125829120);
    unsigned short* gT  = (unsigned short*)(ws + 192937984);

    dim3 blk(256);

    // 0. weights -> bf16 (padded); zero norm accumulators
    hipMemsetAsync(ws + SM, 0, 8192, stream);
    k_wconv<<<288, blk, 0, stream>>>(wqkv, wq_b, 384, 192, 192, 73728);
    k_wconv<<<384, blk, 0, stream>>>(wffni, wfi_b, 510, 192, 192, 98304);
    k_wconv<<<384, blk, 0, stream>>>(wffni + 510 * 192, wfi_b + 512 * 192, 510, 192, 192, 98304);
    k_wconv<<<384, blk, 0, stream>>>(wffno, wfo_b, 192, 510, 512, 98304);

    // 1. LN1 -> xn fp32 + xnT bf16
    k_ln<1><<<256, blk, 0, stream>>>(x, ln1g, ln1b, xn, xnT);

    // 2. SSL: row dwt -> col dwt + band conv -> fused idwt (q bf16 + q^2 sums)
    k_dwt_row<<<768, blk, 0, stream>>>(xn, rowbuf);
    k_dwt_colconv<<<dim3(2, CCH, BB), blk, 0, stream>>>(rowbuf, w5, w7, w9, bfilt);
    k_idwt2<<<dim3(8, CCH, BB), blk, 0, stream>>>(bfilt, q, rq2);

    // 3. kv = dw3x3(conv1x1(xn, w_qkv)) bf16, k^2 sums fused on half 0
    for (int h = 0; h < 2; ++h) {
        k_gemm<1, 0><<<dim3(64, 3, BB), blk, 0, stream>>>(xnT, wq_b + (size_t)h * 192 * 192,
                                                          kvtmp, nullptr, 192, 192, 192, 192, 0);
        if (h == 0)
            k_dw8<1><<<dim3(8, 192, BB), blk, 0, stream>>>(kvtmp, wqkvd, kvb, rk2, 192, 0, 384, 0);
        else
            k_dw8<0><<<dim3(8, 192, BB), blk, 0, stream>>>(kvtmp, wqkvd + 192 * 9, kvb, nullptr, 192, 0, 384, 192);
    }

    // 4. norms + attention weights + fused output weight
    k_fnorm<<<6, blk, 0, stream>>>(rq2, rk2, rq, rk);
    k_qk_mfma<<<dim3(16, 16), blk, 0, stream>>>(q, kvb, pS);
    k_attn_soft<<<16, blk, 0, stream>>>(pS, rq, rk, temp, attnw);
    k_wfuse<<<dim3(192, 4), 192, 0, stream>>>(wattn, attnw, wf_b);

    // 5. d_out = x + (Wattn @ BDattn) @ V : transpose V then one GEMM (kvtmp dead)
    k_transT<192><<<dim3(256, 1, BB), blk, 0, stream>>>(kvb, vT, 384, 192);
    k_gemm<0, 1><<<dim3(64, 3, BB), blk, 0, stream>>>(vT, wf_b, out, x, 192, 192, 192, 192, 36864);

    // 6. xn2T = LN2(d_out)
    k_ln<0><<<256, blk, 0, stream>>>(out, ln2g, ln2b, nullptr, xnT);

    // 7. GDFN in 2 hid-chunks of 256
    for (int ck = 0; ck < 2; ++ck) {
        int validc = (ck == 0) ? 256 : 254;
        k_gemm<1, 0><<<dim3(64, 4, BB), blk, 0, stream>>>(xnT, wfi_b + (size_t)(ck * 256) * 192,
                                                          y1r, nullptr, 192, 192, 192, 256, 0);
        k_gemm<1, 0><<<dim3(64, 4, BB), blk, 0, stream>>>(xnT, wfi_b + (size_t)(512 + ck * 256) * 192,
                                                          y2r, nullptr, 192, 192, 192, 256, 0);
        k_dw8gate<<<dim3(8, 256, BB), blk, 0, stream>>>(y1r, y2r, wffnd + (size_t)(ck * 256) * 9,
                                                        wffnd + (size_t)(510 + ck * 256) * 9, gg, validc);
        k_transT<256><<<dim3(256, 1, BB), blk, 0, stream>>>(gg, gT, 256, 0);
        k_gemm<0, 1><<<dim3(64, 3, BB), blk, 0, stream>>>(gT, wfo_b + ck * 256, out, out, 256, 256, 512, 192, 0);
    }
}